// Round 16
// baseline (182.773 us; speedup 1.0000x reference)
//
#include <hip/hip_runtime.h>
#include <hip/hip_bf16.h>

// Pipeline (N=50000, E=1.6M, D=16, NK=2):
//   bhist/bscan: bucket (dst>>7) histogram + scan -> bbase/bcur/off sentinel
//   partA: bucket-partition edges into PACKED staging (sd=src|dst<<16, k f2)
//   partB: per-128-node-bucket sort -> srcS/kS + off (hist pass reads 4B/edge)
//   conv1+mlp1: half-wave/node, 16-lane group per edge, dual k-acc
//   conv2:      wave per node, 8-lane group per edge, 4-deep gather ILP
//   packW+mlp2: MFMA path (R15) — 32x mfma_16x16x32_bf16 per wave
//
// NOTE (round-7): NEVER atomicAdd on __shared__ float in hot loops (678us).
// NOTE (mlp2 R8-R14): vector-ALU mlp2 plateaued 45-56us; MFMA fixed it (~15us).
// NOTE (R16): src,dst < 2^16 -> 12B staging records; partB hist reads sd only.

#define EPSV 1e-12f
#define CHUNK 2048      // edges per partA block
#define NB2 512         // bucket slot array size (nbuck = ceil(N/128) = 391)
#define BSH 7           // bucket shift: 128 nodes per bucket
#define BNODES 128      // nodes per bucket
#define BCPAD 16        // bcur padding stride (ints)

typedef unsigned short ushort_t;
typedef unsigned int uint_t;
typedef __attribute__((ext_vector_type(8))) short bf16x8;
typedef __attribute__((ext_vector_type(4))) float f32x4;

// ---- detect whether edge_index buffer is int64 (odd int32 words all zero) ----
__global__ void detect_i64_kernel(const int* ei, int* flag) {
    int lane = threadIdx.x;
    int nonzero = 0;
    for (int i = lane; i < 1024; i += 64) {
        if (ei[2 * i + 1] != 0) nonzero = 1;
    }
    unsigned long long b = __ballot(nonzero);
    if (lane == 0) *flag = (b == 0ull) ? 1 : 0;   // 1 => int64 layout
}

__device__ __forceinline__ void load_edge(const int* ei, int e, int E, int flag,
                                          int& src, int& dst) {
    if (flag) {            // int64 storage: low words at even int32 indices
        src = ei[2 * e];
        dst = ei[2 * E + 2 * e];
    } else {               // int32 storage
        src = ei[e];
        dst = ei[E + e];
    }
}

// ---- bucket histogram: LDS-privatized, vectorized dst loads ----
__global__ __launch_bounds__(256) void bhist_kernel(
        const int* __restrict__ ei, const int* __restrict__ flagp,
        int* __restrict__ cntmat, int E) {
    __shared__ int l[NB2];
    for (int i = threadIdx.x; i < NB2; i += 256) l[i] = 0;
    __syncthreads();
    int flag = *flagp;
    int stride = gridDim.x * 256;
    int gid = blockIdx.x * 256 + threadIdx.x;
    if ((E & 3) == 0) {
        if (flag) {
            const int4* p = (const int4*)(ei + 2 * (size_t)E);  // dst pairs
            int total = E >> 1;
            for (int i = gid; i < total; i += stride) {
                int4 v = p[i];
                atomicAdd(&l[v.x >> BSH], 1);
                atomicAdd(&l[v.z >> BSH], 1);
            }
        } else {
            const int4* p = (const int4*)(ei + (size_t)E);
            int total = E >> 2;
            for (int i = gid; i < total; i += stride) {
                int4 v = p[i];
                atomicAdd(&l[v.x >> BSH], 1);
                atomicAdd(&l[v.y >> BSH], 1);
                atomicAdd(&l[v.z >> BSH], 1);
                atomicAdd(&l[v.w >> BSH], 1);
            }
        }
    } else {
        for (int e = gid; e < E; e += stride) {
            int dst = flag ? ei[2 * (size_t)E + 2 * e] : ei[(size_t)E + e];
            atomicAdd(&l[dst >> BSH], 1);
        }
    }
    __syncthreads();
    for (int i = threadIdx.x; i < NB2; i += 256)
        cntmat[blockIdx.x * NB2 + i] = l[i];
}

// ---- column-sum cntmat + exclusive scan of bucket counts (512 threads) ----
__global__ __launch_bounds__(NB2) void bscan_kernel(
        const int* __restrict__ cntmat,
        int* __restrict__ bbase, int* __restrict__ bcur,
        int* __restrict__ off,
        int nbuck, int E, int nrows, int N) {
    __shared__ int s[NB2];
    int t = threadIdx.x;            // blockDim = NB2
    int c = 0;
    for (int i = 0; i < nrows; ++i) c += cntmat[i * NB2 + t];
    s[t] = c;
    __syncthreads();
    for (int d = 1; d < NB2; d <<= 1) {
        int v = (t >= d) ? s[t - d] : 0;
        __syncthreads();
        s[t] += v;
        __syncthreads();
    }
    int excl = s[t] - c;
    if (t < nbuck) { bbase[t] = excl; bcur[t * BCPAD] = excl; }
    if (t == 0) { bbase[nbuck] = E; off[N] = E; }
}

// ---- partA: bucket-partition edges by dst>>7; PACKED 12B records ----
__global__ __launch_bounds__(256) void partA_kernel(
        const float* __restrict__ K, const int* __restrict__ ei,
        const int* __restrict__ flagp, int* __restrict__ bcur,
        uint_t* __restrict__ stgSD, float2* __restrict__ stgK, int E) {
    __shared__ int cnt[NB2];
    __shared__ int bexc[NB2];
    __shared__ int gbase[NB2];
    __shared__ int scanbuf[256];
    __shared__ uint_t stageSD[CHUNK];   // 8 KB
    __shared__ float2 stageK[CHUNK];    // 16 KB

    int flag = *flagp;
    int e0 = blockIdx.x * CHUNK;
    int tot = min(CHUNK, E - e0);
    int t = threadIdx.x;

    for (int b = t; b < NB2; b += 256) cnt[b] = 0;
    __syncthreads();

    int    myslot[CHUNK / 256];
    int    mybk[CHUNK / 256];
    uint_t mysd[CHUNK / 256];
    float2 myk[CHUNK / 256];
#pragma unroll
    for (int it = 0; it < CHUNK / 256; ++it) {
        int e = e0 + it * 256 + t;
        mybk[it] = -1;
        if (e < E) {
            int src, dst;
            load_edge(ei, e, E, flag, src, dst);
            int bk = dst >> BSH;
            mybk[it] = bk;
            mysd[it] = (uint_t)src | ((uint_t)dst << 16);
            myk[it] = make_float2(K[e], K[E + e]);
            myslot[it] = atomicAdd(&cnt[bk], 1);
        }
    }
    __syncthreads();

    // scan 512 buckets: thread t owns buckets 2t, 2t+1
    int c0 = cnt[2 * t];
    int c1 = cnt[2 * t + 1];
    int cs = c0 + c1;
    scanbuf[t] = cs;
    __syncthreads();
    for (int d = 1; d < 256; d <<= 1) {
        int v = (t >= d) ? scanbuf[t - d] : 0;
        __syncthreads();
        scanbuf[t] += v;
        __syncthreads();
    }
    int excl = scanbuf[t] - cs;
    bexc[2 * t] = excl;
    bexc[2 * t + 1] = excl + c0;
    gbase[2 * t]     = c0 ? atomicAdd(&bcur[(2 * t) * BCPAD], c0) : 0;
    gbase[2 * t + 1] = c1 ? atomicAdd(&bcur[(2 * t + 1) * BCPAD], c1) : 0;
    __syncthreads();

#pragma unroll
    for (int it = 0; it < CHUNK / 256; ++it) {
        if (mybk[it] >= 0) {
            int pos = bexc[mybk[it]] + myslot[it];
            stageSD[pos] = mysd[it];
            stageK[pos] = myk[it];
        }
    }
    __syncthreads();

    for (int i = t; i < tot; i += 256) {
        uint_t sd = stageSD[i];
        int bk = (int)(sd >> 16) >> BSH;
        int pos = gbase[bk] + (i - bexc[bk]);
        stgSD[pos] = sd;
        stgK[pos] = stageK[i];
    }
}

// ---- partB: one block per 128-node bucket; hist pass reads 4B/edge ----
__global__ __launch_bounds__(256) void partB_kernel(
        const uint_t* __restrict__ stgSD, const float2* __restrict__ stgK,
        const int* __restrict__ bbase,
        int* __restrict__ off, int* __restrict__ srcS,
        float2* __restrict__ kS, int N) {
    __shared__ int lcnt[BNODES];
    __shared__ int lscan[BNODES];

    int b = blockIdx.x;
    int nodeBase = b << BSH;
    int s0 = bbase[b];
    int s1 = bbase[b + 1];
    int t = threadIdx.x;

    if (t < BNODES) lcnt[t] = 0;
    __syncthreads();

    for (int i = s0 + t; i < s1; i += 256)
        atomicAdd(&lcnt[(stgSD[i] >> 16) & (BNODES - 1)], 1);
    __syncthreads();

    if (t < BNODES) lscan[t] = lcnt[t];
    __syncthreads();
    for (int d = 1; d < BNODES; d <<= 1) {
        int v = 0;
        if (t < BNODES && t >= d) v = lscan[t - d];
        __syncthreads();
        if (t < BNODES) lscan[t] += v;
        __syncthreads();
    }
    if (t < BNODES) {
        int node = nodeBase + t;
        if (node < N) {
            int c = lcnt[t];
            int o = s0 + lscan[t] - c;   // exclusive offset, absolute
            off[node] = o;
            lcnt[t] = o;                 // becomes the cursor
        }
    }
    __syncthreads();

    for (int i = s0 + t; i < s1; i += 256) {
        uint_t sd = stgSD[i];
        float2 kk = stgK[i];
        int pos = atomicAdd(&lcnt[(sd >> 16) & (BNODES - 1)], 1);
        srcS[pos] = (int)(sd & 0xFFFFu);
        kS[pos] = kk;
    }
}

// ---- conv1 + MLP1: half-wave per node; 16-lane group per edge ----
__global__ __launch_bounds__(256) void conv1_mlp1_kernel(
        const float* __restrict__ x, const int* __restrict__ srcS,
        const float2* __restrict__ kS, const int* __restrict__ off,
        const float* __restrict__ W1, const float* __restrict__ b1,
        float* __restrict__ h1, int N) {
    __shared__ float w[1024];
    __shared__ float bsh[32];
    for (int i = threadIdx.x; i < 1024; i += 256) w[i] = W1[i];
    if (threadIdx.x < 32) bsh[threadIdx.x] = b1[threadIdx.x];
    __syncthreads();

    int hw = threadIdx.x >> 5;        // half-wave 0..7 -> node
    int lane = threadIdx.x & 31;
    int node = blockIdx.x * 8 + hw;
    if (node >= N) return;

    int ch = lane & 15;
    int grp = lane >> 4;              // 0/1: edge parity
    int start = off[node];
    int deg = off[node + 1] - start;

    float a0 = 0.f, a1 = 0.f;
    int j = grp;
    for (; j + 6 < deg; j += 8) {     // edges j, j+2, j+4, j+6
        int p = start + j;
        int s0 = srcS[p], s1 = srcS[p + 2], s2 = srcS[p + 4], s3 = srcS[p + 6];
        float2 k0 = kS[p], k1 = kS[p + 2], k2 = kS[p + 4], k3 = kS[p + 6];
        float v0 = x[s0 * 16 + ch];
        float v1 = x[s1 * 16 + ch];
        float v2 = x[s2 * 16 + ch];
        float v3 = x[s3 * 16 + ch];
        a0 += k0.x * v0; a1 += k0.y * v0;
        a0 += k1.x * v1; a1 += k1.y * v1;
        a0 += k2.x * v2; a1 += k2.y * v2;
        a0 += k3.x * v3; a1 += k3.y * v3;
    }
    for (; j < deg; j += 2) {
        int p = start + j;
        int s = srcS[p];
        float2 kk = kS[p];
        float v = x[s * 16 + ch];
        a0 += kk.x * v; a1 += kk.y * v;
    }
    a0 += __shfl_xor(a0, 16, 32);
    a1 += __shfl_xor(a1, 16, 32);
    float acc = grp ? a1 : a0;

    float o = bsh[lane];
#pragma unroll
    for (int q = 0; q < 32; q++) o += __shfl(acc, q, 32) * w[q * 32 + lane];
    o = fmaxf(o, 0.f);
    float ss = o * o;
#pragma unroll
    for (int m = 16; m >= 1; m >>= 1) ss += __shfl_xor(ss, m, 32);
    h1[node * 32 + lane] = o / fmaxf(sqrtf(ss), EPSV);
}

// ---- conv2: wave per node; 8-lane group per edge; 4-deep gather ILP ----
__global__ __launch_bounds__(256) void conv2_gather_kernel(
        const float* __restrict__ h1, const int* __restrict__ srcS,
        const float2* __restrict__ kS, const int* __restrict__ off,
        float* __restrict__ h2, int N) {
    int wid = threadIdx.x >> 6;
    int lane = threadIdx.x & 63;
    int node = blockIdx.x * 4 + wid;
    if (node >= N) return;

    int grp = lane >> 3;              // 0..7: edge index mod 8
    int cq = lane & 7;                // channel quad: ch = cq*4..cq*4+3
    int start = off[node];
    int deg = off[node + 1] - start;

    float a00 = 0.f, a01 = 0.f, a02 = 0.f, a03 = 0.f;   // k0 * row[cq*4..]
    float a10 = 0.f, a11 = 0.f, a12 = 0.f, a13 = 0.f;   // k1 * row[cq*4..]
    int j = grp;
    for (; j + 24 < deg; j += 32) {   // edges j, j+8, j+16, j+24
        int p0 = start + j, p1 = p0 + 8, p2 = p0 + 16, p3 = p0 + 24;
        int s0 = srcS[p0], s1 = srcS[p1], s2 = srcS[p2], s3 = srcS[p3];
        float2 k0 = kS[p0], k1 = kS[p1], k2 = kS[p2], k3 = kS[p3];
        float4 v0 = *(const float4*)&h1[s0 * 32 + cq * 4];
        float4 v1 = *(const float4*)&h1[s1 * 32 + cq * 4];
        float4 v2 = *(const float4*)&h1[s2 * 32 + cq * 4];
        float4 v3 = *(const float4*)&h1[s3 * 32 + cq * 4];
        a00 += k0.x * v0.x; a01 += k0.x * v0.y; a02 += k0.x * v0.z; a03 += k0.x * v0.w;
        a10 += k0.y * v0.x; a11 += k0.y * v0.y; a12 += k0.y * v0.z; a13 += k0.y * v0.w;
        a00 += k1.x * v1.x; a01 += k1.x * v1.y; a02 += k1.x * v1.z; a03 += k1.x * v1.w;
        a10 += k1.y * v1.x; a11 += k1.y * v1.y; a12 += k1.y * v1.z; a13 += k1.y * v1.w;
        a00 += k2.x * v2.x; a01 += k2.x * v2.y; a02 += k2.x * v2.z; a03 += k2.x * v2.w;
        a10 += k2.y * v2.x; a11 += k2.y * v2.y; a12 += k2.y * v2.z; a13 += k2.y * v2.w;
        a00 += k3.x * v3.x; a01 += k3.x * v3.y; a02 += k3.x * v3.z; a03 += k3.x * v3.w;
        a10 += k3.y * v3.x; a11 += k3.y * v3.y; a12 += k3.y * v3.z; a13 += k3.y * v3.w;
    }
    for (; j + 8 < deg; j += 16) {    // edges j, j+8
        int p0 = start + j, p1 = p0 + 8;
        int s0 = srcS[p0], s1 = srcS[p1];
        float2 k0 = kS[p0], k1 = kS[p1];
        float4 v0 = *(const float4*)&h1[s0 * 32 + cq * 4];
        float4 v1 = *(const float4*)&h1[s1 * 32 + cq * 4];
        a00 += k0.x * v0.x; a01 += k0.x * v0.y; a02 += k0.x * v0.z; a03 += k0.x * v0.w;
        a10 += k0.y * v0.x; a11 += k0.y * v0.y; a12 += k0.y * v0.z; a13 += k0.y * v0.w;
        a00 += k1.x * v1.x; a01 += k1.x * v1.y; a02 += k1.x * v1.z; a03 += k1.x * v1.w;
        a10 += k1.y * v1.x; a11 += k1.y * v1.y; a12 += k1.y * v1.z; a13 += k1.y * v1.w;
    }
    for (; j < deg; j += 8) {
        int p = start + j;
        int s = srcS[p];
        float2 kk = kS[p];
        float4 v = *(const float4*)&h1[s * 32 + cq * 4];
        a00 += kk.x * v.x; a01 += kk.x * v.y; a02 += kk.x * v.z; a03 += kk.x * v.w;
        a10 += kk.y * v.x; a11 += kk.y * v.y; a12 += kk.y * v.z; a13 += kk.y * v.w;
    }

#pragma unroll
    for (int m = 8; m < 64; m <<= 1) {
        a00 += __shfl_xor(a00, m, 64); a01 += __shfl_xor(a01, m, 64);
        a02 += __shfl_xor(a02, m, 64); a03 += __shfl_xor(a03, m, 64);
        a10 += __shfl_xor(a10, m, 64); a11 += __shfl_xor(a11, m, 64);
        a12 += __shfl_xor(a12, m, 64); a13 += __shfl_xor(a13, m, 64);
    }
    if (grp == 0) {
        float4 o = make_float4(a00, a01, a02, a03);
        *(float4*)&h2[(size_t)node * 64 + cq * 4] = o;
    } else if (grp == 1) {
        float4 o = make_float4(a10, a11, a12, a13);
        *(float4*)&h2[(size_t)node * 64 + 32 + cq * 4] = o;
    }
}

// ---- bf16 helpers ----
__device__ __forceinline__ ushort_t f2bf(float f) {
    uint_t u = __float_as_uint(f);
    uint_t r = u + 0x7FFFu + ((u >> 16) & 1u);
    return (ushort_t)(r >> 16);
}
__device__ __forceinline__ bf16x8 ld_frag(const uint4* p) {
    union { uint4 q; bf16x8 v; } u;
    u.q = *p;
    return u.v;
}

// ---- packW: W2a/W2b -> MFMA B-fragment order (bf16, coalesced uint4) ----
__global__ __launch_bounds__(256) void packW_kernel(
        const float* __restrict__ W2a, const float* __restrict__ W2b,
        uint4* __restrict__ wpkA, uint4* __restrict__ wpkB) {
    int gid = blockIdx.x * 256 + threadIdx.x;    // 0..2047
    if (gid < 1024) {
        int ct = gid >> 7, ks = (gid >> 6) & 1, l = gid & 63;
        int kb = l >> 4, m = l & 15;
        ushort_t us[8];
#pragma unroll
        for (int i = 0; i < 8; i++)
            us[i] = f2bf(W2a[(size_t)(ks * 32 + kb * 8 + i) * 128 + ct * 16 + m]);
        uint4 q;
        q.x = (uint_t)us[0] | ((uint_t)us[1] << 16);
        q.y = (uint_t)us[2] | ((uint_t)us[3] << 16);
        q.z = (uint_t)us[4] | ((uint_t)us[5] << 16);
        q.w = (uint_t)us[6] | ((uint_t)us[7] << 16);
        wpkA[gid] = q;
    } else {
        int e = gid - 1024;
        int ct = e >> 8, ks = (e >> 6) & 3, l = e & 63;
        int kb = l >> 4, m = l & 15;
        ushort_t us[8];
#pragma unroll
        for (int i = 0; i < 8; i++)
            us[i] = f2bf(W2b[(size_t)(ks * 32 + kb * 8 + i) * 64 + ct * 16 + m]);
        uint4 q;
        q.x = (uint_t)us[0] | ((uint_t)us[1] << 16);
        q.y = (uint_t)us[2] | ((uint_t)us[3] << 16);
        q.z = (uint_t)us[4] | ((uint_t)us[5] << 16);
        q.w = (uint_t)us[6] | ((uint_t)us[7] << 16);
        wpkB[e] = q;
    }
}

// ---- MLP2 via MFMA: 64 nodes/block, 4 waves x 16 nodes each ----
__global__ __launch_bounds__(256) void mlp2_kernel(
        const float* __restrict__ h2, const uint4* __restrict__ wpkA,
        const float* __restrict__ b2a, const uint4* __restrict__ wpkB,
        const float* __restrict__ b2b, float* __restrict__ out, int N) {
    __shared__ ushort_t hs[64 * 136];   // 17.4 KB

    int tid = threadIdx.x;
    int w = tid >> 6;          // wave 0..3 -> 16-node M-tile
    int l = tid & 63;
    int m = l & 15;
    int kb = l >> 4;           // 0..3
    int rowbase = w * 16;
    int n0 = blockIdx.x * 64;
    int anode = n0 + rowbase + m;      // A-side node for this lane
    bool alive = anode < N;

    // A-frags for GEMM1 (K=64 -> 2 steps) from global X
    bf16x8 a1[2];
#pragma unroll
    for (int ks = 0; ks < 2; ks++) {
        float4 xa = make_float4(0.f, 0.f, 0.f, 0.f), xb = xa;
        if (alive) {
            xa = *(const float4*)&h2[(size_t)anode * 64 + ks * 32 + kb * 8];
            xb = *(const float4*)&h2[(size_t)anode * 64 + ks * 32 + kb * 8 + 4];
        }
        bf16x8 a;
        a[0] = (short)f2bf(xa.x); a[1] = (short)f2bf(xa.y);
        a[2] = (short)f2bf(xa.z); a[3] = (short)f2bf(xa.w);
        a[4] = (short)f2bf(xb.x); a[5] = (short)f2bf(xb.y);
        a[6] = (short)f2bf(xb.z); a[7] = (short)f2bf(xb.w);
        a1[ks] = a;
    }

    // GEMM1: 8 col-tiles x (2 MFMA) -> H[16][128] bf16 in LDS
#pragma unroll
    for (int ct = 0; ct < 8; ct++) {
        f32x4 acc = {0.f, 0.f, 0.f, 0.f};
        acc = __builtin_amdgcn_mfma_f32_16x16x32_bf16(
                  a1[0], ld_frag(&wpkA[(ct * 2 + 0) * 64 + l]), acc, 0, 0, 0);
        acc = __builtin_amdgcn_mfma_f32_16x16x32_bf16(
                  a1[1], ld_frag(&wpkA[(ct * 2 + 1) * 64 + l]), acc, 0, 0, 0);
        float bias = b2a[ct * 16 + m];
#pragma unroll
        for (int r = 0; r < 4; r++) {
            float hv = fmaxf(acc[r] + bias, 0.f);
            hs[(rowbase + kb * 4 + r) * 136 + ct * 16 + m] = f2bf(hv);
        }
    }
    __syncthreads();

    // A-frags for GEMM2 (K=128 -> 4 steps) from LDS (16B-aligned b128)
    bf16x8 a2[4];
#pragma unroll
    for (int ks = 0; ks < 4; ks++) {
        union { uint4 q; bf16x8 v; } u;
        u.q = *(const uint4*)&hs[(rowbase + m) * 136 + ks * 32 + kb * 8];
        a2[ks] = u.v;
    }

    // GEMM2: 4 col-tiles x (4 MFMA)
    f32x4 acc2[4];
#pragma unroll
    for (int ct = 0; ct < 4; ct++) {
        f32x4 acc = {0.f, 0.f, 0.f, 0.f};
#pragma unroll
        for (int ks = 0; ks < 4; ks++)
            acc = __builtin_amdgcn_mfma_f32_16x16x32_bf16(
                      a2[ks], ld_frag(&wpkB[(ct * 4 + ks) * 64 + l]), acc, 0, 0, 0);
        float bias = b2b[ct * 16 + m];
#pragma unroll
        for (int r = 0; r < 4; r++) acc2[ct][r] = acc[r] + bias;
    }

    // l2norm: lane holds rows kb*4+r, cols {ct*16+m}
#pragma unroll
    for (int r = 0; r < 4; r++) {
        float ss = acc2[0][r] * acc2[0][r] + acc2[1][r] * acc2[1][r] +
                   acc2[2][r] * acc2[2][r] + acc2[3][r] * acc2[3][r];
        ss += __shfl_xor(ss, 1, 16);
        ss += __shfl_xor(ss, 2, 16);
        ss += __shfl_xor(ss, 4, 16);
        ss += __shfl_xor(ss, 8, 16);
        float invn = 1.0f / fmaxf(sqrtf(ss), EPSV);
        int nrow = n0 + rowbase + kb * 4 + r;
        if (nrow < N) {
#pragma unroll
            for (int ct = 0; ct < 4; ct++)
                out[(size_t)nrow * 64 + ct * 16 + m] = acc2[ct][r] * invn;
        }
    }
}

extern "C" void kernel_launch(void* const* d_in, const int* in_sizes, int n_in,
                              void* d_out, int out_size, void* d_ws, size_t ws_size,
                              hipStream_t stream) {
    const float* x   = (const float*)d_in[0];
    const float* K   = (const float*)d_in[1];
    const int*   ei  = (const int*)d_in[2];
    const float* W1  = (const float*)d_in[3];
    const float* b1  = (const float*)d_in[4];
    const float* W2a = (const float*)d_in[5];
    const float* b2a = (const float*)d_in[6];
    const float* W2b = (const float*)d_in[7];
    const float* b2b = (const float*)d_in[8];
    float* out = (float*)d_out;

    const int D  = 16;
    const int NK = 2;
    const int N  = in_sizes[0] / D;        // 50000 (src,dst < 2^16 assumed)
    const int E  = in_sizes[1] / NK;       // 1600000
    const int nbuck = (N + BNODES - 1) >> BSH;  // 391 <= NB2
    const int HROWS = 256;                 // bhist blocks

    // workspace layout:
    //   region0 (overlaid in time):
    //     phase 1 (CSR build): stgK float2[E] | stgSD uint[E]   (E*12 bytes)
    //     phase 2+3:           h2[N*64] | h1[N*32]              (N*384 bytes)
    //   then: srcS[E] | kS[E] (float2) | off[N+1] | cntmat[HROWS*NB2] |
    //         bbase[NB2+1] | bcur[NB2*BCPAD] | flag[1] | wpkA[1024] | wpkB[1024]
    size_t region0 = (size_t)E * 12;
    size_t hbytes  = (size_t)N * 96 * 4;
    if (hbytes > region0) region0 = hbytes;

    float* h2       = (float*)d_ws;
    float* h1       = h2 + (size_t)N * 64;
    float2* stgK    = (float2*)d_ws;                  // phase 1
    uint_t* stgSD   = (uint_t*)(stgK + (size_t)E);    // phase 1
    int* srcS       = (int*)((char*)d_ws + region0);
    float2* kS      = (float2*)(srcS + (size_t)E);
    int* off        = (int*)(kS + (size_t)E);
    int* cntmat     = off + (N + 1);
    int* bbase      = cntmat + HROWS * NB2;
    int* bcur       = bbase + NB2 + 1;
    int* flag       = bcur + NB2 * BCPAD;
    char* wp        = (char*)(flag + 1);
    wp = (char*)(((size_t)wp + 15) & ~(size_t)15);
    uint4* wpkA     = (uint4*)wp;
    uint4* wpkB     = wpkA + 1024;

    detect_i64_kernel<<<1, 64, 0, stream>>>(ei, flag);
    packW_kernel<<<8, 256, 0, stream>>>(W2a, W2b, wpkA, wpkB);
    bhist_kernel<<<HROWS, 256, 0, stream>>>(ei, flag, cntmat, E);
    bscan_kernel<<<1, NB2, 0, stream>>>(cntmat, bbase, bcur, off,
                                        nbuck, E, HROWS, N);

    int ablocks = (E + CHUNK - 1) / CHUNK;
    partA_kernel<<<ablocks, 256, 0, stream>>>(K, ei, flag, bcur,
                                              stgSD, stgK, E);
    partB_kernel<<<nbuck, 256, 0, stream>>>(stgSD, stgK, bbase, off,
                                            srcS, kS, N);

    conv1_mlp1_kernel<<<(N + 7) / 8, 256, 0, stream>>>(x, srcS, kS, off,
                                                       W1, b1, h1, N);
    conv2_gather_kernel<<<(N + 3) / 4, 256, 0, stream>>>(h1, srcS, kS, off,
                                                         h2, N);
    mlp2_kernel<<<(N + 63) / 64, 256, 0, stream>>>(h2, wpkA, b2a, wpkB, b2b,
                                                   out, N);
}

// Round 17
// 178.687 us; speedup vs baseline: 1.0229x; 1.0229x over previous
//
#include <hip/hip_runtime.h>
#include <hip/hip_bf16.h>

// Pipeline (N=50000, E=1.6M, D=16, NK=2):
//   bhist/bscan: bucket (dst>>7) histogram + scan -> bbase/bcur/off sentinel
//   partA: bucket-partition edges into PACKED staging (sd=src|dst<<16, k f2)
//   partB: per-128-node-bucket sort -> srcU(u16)/kS + off
//   conv1+mlp1: half-wave/node, 16-lane group/edge -> h1 BF16 (L2-fits: 3.2MB)
//   conv2:      wave/node, 8-lane group/edge, bf16 row gather -> h2 BF16
//   packW+mlp2: MFMA path; h2 bf16 IS the A-fragment (no conversion)
//
// NOTE (round-7): NEVER atomicAdd on __shared__ float in hot loops (678us).
// NOTE (mlp2 R8-R14): vector-ALU mlp2 plateaued 45-56us; MFMA fixed it.
// NOTE (R17): conv2 was BW-bound on h1 gather (205MB, h1 f32 > 4MB L2/XCD).
//   h1/h2 bf16 halves gather+handoff bytes; h2 bf16 is error-free (mlp2
//   rounded h2 to bf16 anyway). srcS ushort is lossless (N < 2^16).

#define EPSV 1e-12f
#define CHUNK 2048      // edges per partA block
#define NB2 512         // bucket slot array size (nbuck = ceil(N/128) = 391)
#define BSH 7           // bucket shift: 128 nodes per bucket
#define BNODES 128      // nodes per bucket
#define BCPAD 16        // bcur padding stride (ints)

typedef unsigned short ushort_t;
typedef unsigned int uint_t;
typedef __attribute__((ext_vector_type(8))) short bf16x8;
typedef __attribute__((ext_vector_type(4))) float f32x4;

// ---- per-block detection of int64 edge_index layout ----
__device__ __forceinline__ int detect_i64_block(const int* ei) {
    __shared__ int nz;
    if (threadIdx.x == 0) nz = 0;
    __syncthreads();
    int v = 0;
    for (int i = threadIdx.x; i < 1024; i += blockDim.x) v |= ei[2 * i + 1];
    if (v) atomicOr(&nz, 1);
    __syncthreads();
    return nz ? 0 : 1;     // 1 => int64 layout
}

__device__ __forceinline__ void load_edge(const int* ei, int e, int E, int flag,
                                          int& src, int& dst) {
    if (flag) {            // int64 storage: low words at even int32 indices
        src = ei[2 * e];
        dst = ei[2 * E + 2 * e];
    } else {               // int32 storage
        src = ei[e];
        dst = ei[E + e];
    }
}

// ---- bf16 helpers ----
__device__ __forceinline__ ushort_t f2bf(float f) {
    uint_t u = __float_as_uint(f);
    uint_t r = u + 0x7FFFu + ((u >> 16) & 1u);
    return (ushort_t)(r >> 16);
}
__device__ __forceinline__ float unpk_lo(uint_t u) {
    return __uint_as_float(u << 16);
}
__device__ __forceinline__ float unpk_hi(uint_t u) {
    return __uint_as_float(u & 0xFFFF0000u);
}
__device__ __forceinline__ bf16x8 ld_frag(const uint4* p) {
    union { uint4 q; bf16x8 v; } u;
    u.q = *p;
    return u.v;
}

// ---- bucket histogram: LDS-privatized, vectorized dst loads ----
__global__ __launch_bounds__(256) void bhist_kernel(
        const int* __restrict__ ei, int* __restrict__ cntmat, int E) {
    __shared__ int l[NB2];
    int flag = detect_i64_block(ei);
    for (int i = threadIdx.x; i < NB2; i += 256) l[i] = 0;
    __syncthreads();
    int stride = gridDim.x * 256;
    int gid = blockIdx.x * 256 + threadIdx.x;
    if ((E & 3) == 0) {
        if (flag) {
            const int4* p = (const int4*)(ei + 2 * (size_t)E);  // dst pairs
            int total = E >> 1;
            for (int i = gid; i < total; i += stride) {
                int4 v = p[i];
                atomicAdd(&l[v.x >> BSH], 1);
                atomicAdd(&l[v.z >> BSH], 1);
            }
        } else {
            const int4* p = (const int4*)(ei + (size_t)E);
            int total = E >> 2;
            for (int i = gid; i < total; i += stride) {
                int4 v = p[i];
                atomicAdd(&l[v.x >> BSH], 1);
                atomicAdd(&l[v.y >> BSH], 1);
                atomicAdd(&l[v.z >> BSH], 1);
                atomicAdd(&l[v.w >> BSH], 1);
            }
        }
    } else {
        for (int e = gid; e < E; e += stride) {
            int dst = flag ? ei[2 * (size_t)E + 2 * e] : ei[(size_t)E + e];
            atomicAdd(&l[dst >> BSH], 1);
        }
    }
    __syncthreads();
    for (int i = threadIdx.x; i < NB2; i += 256)
        cntmat[blockIdx.x * NB2 + i] = l[i];
}

// ---- column-sum cntmat + exclusive scan of bucket counts (512 threads) ----
__global__ __launch_bounds__(NB2) void bscan_kernel(
        const int* __restrict__ cntmat,
        int* __restrict__ bbase, int* __restrict__ bcur,
        int* __restrict__ off,
        int nbuck, int E, int nrows, int N) {
    __shared__ int s[NB2];
    int t = threadIdx.x;            // blockDim = NB2
    int c = 0;
    for (int i = 0; i < nrows; ++i) c += cntmat[i * NB2 + t];
    s[t] = c;
    __syncthreads();
    for (int d = 1; d < NB2; d <<= 1) {
        int v = (t >= d) ? s[t - d] : 0;
        __syncthreads();
        s[t] += v;
        __syncthreads();
    }
    int excl = s[t] - c;
    if (t < nbuck) { bbase[t] = excl; bcur[t * BCPAD] = excl; }
    if (t == 0) { bbase[nbuck] = E; off[N] = E; }
}

// ---- partA: bucket-partition edges by dst>>7; PACKED 12B records ----
__global__ __launch_bounds__(256) void partA_kernel(
        const float* __restrict__ K, const int* __restrict__ ei,
        int* __restrict__ bcur,
        uint_t* __restrict__ stgSD, float2* __restrict__ stgK, int E) {
    __shared__ int cnt[NB2];
    __shared__ int bexc[NB2];
    __shared__ int gbase[NB2];
    __shared__ int scanbuf[256];
    __shared__ uint_t stageSD[CHUNK];   // 8 KB
    __shared__ float2 stageK[CHUNK];    // 16 KB

    int flag = detect_i64_block(ei);
    int e0 = blockIdx.x * CHUNK;
    int tot = min(CHUNK, E - e0);
    int t = threadIdx.x;

    for (int b = t; b < NB2; b += 256) cnt[b] = 0;
    __syncthreads();

    int    myslot[CHUNK / 256];
    int    mybk[CHUNK / 256];
    uint_t mysd[CHUNK / 256];
    float2 myk[CHUNK / 256];
#pragma unroll
    for (int it = 0; it < CHUNK / 256; ++it) {
        int e = e0 + it * 256 + t;
        mybk[it] = -1;
        if (e < E) {
            int src, dst;
            load_edge(ei, e, E, flag, src, dst);
            int bk = dst >> BSH;
            mybk[it] = bk;
            mysd[it] = (uint_t)src | ((uint_t)dst << 16);
            myk[it] = make_float2(K[e], K[E + e]);
            myslot[it] = atomicAdd(&cnt[bk], 1);
        }
    }
    __syncthreads();

    // scan 512 buckets: thread t owns buckets 2t, 2t+1
    int c0 = cnt[2 * t];
    int c1 = cnt[2 * t + 1];
    int cs = c0 + c1;
    scanbuf[t] = cs;
    __syncthreads();
    for (int d = 1; d < 256; d <<= 1) {
        int v = (t >= d) ? scanbuf[t - d] : 0;
        __syncthreads();
        scanbuf[t] += v;
        __syncthreads();
    }
    int excl = scanbuf[t] - cs;
    bexc[2 * t] = excl;
    bexc[2 * t + 1] = excl + c0;
    gbase[2 * t]     = c0 ? atomicAdd(&bcur[(2 * t) * BCPAD], c0) : 0;
    gbase[2 * t + 1] = c1 ? atomicAdd(&bcur[(2 * t + 1) * BCPAD], c1) : 0;
    __syncthreads();

#pragma unroll
    for (int it = 0; it < CHUNK / 256; ++it) {
        if (mybk[it] >= 0) {
            int pos = bexc[mybk[it]] + myslot[it];
            stageSD[pos] = mysd[it];
            stageK[pos] = myk[it];
        }
    }
    __syncthreads();

    for (int i = t; i < tot; i += 256) {
        uint_t sd = stageSD[i];
        int bk = (int)(sd >> 16) >> BSH;
        int pos = gbase[bk] + (i - bexc[bk]);
        stgSD[pos] = sd;
        stgK[pos] = stageK[i];
    }
}

// ---- partB: one block per 128-node bucket; hist pass reads 4B/edge ----
__global__ __launch_bounds__(256) void partB_kernel(
        const uint_t* __restrict__ stgSD, const float2* __restrict__ stgK,
        const int* __restrict__ bbase,
        int* __restrict__ off, ushort_t* __restrict__ srcU,
        float2* __restrict__ kS, int N) {
    __shared__ int lcnt[BNODES];
    __shared__ int lscan[BNODES];

    int b = blockIdx.x;
    int nodeBase = b << BSH;
    int s0 = bbase[b];
    int s1 = bbase[b + 1];
    int t = threadIdx.x;

    if (t < BNODES) lcnt[t] = 0;
    __syncthreads();

    for (int i = s0 + t; i < s1; i += 256)
        atomicAdd(&lcnt[(stgSD[i] >> 16) & (BNODES - 1)], 1);
    __syncthreads();

    if (t < BNODES) lscan[t] = lcnt[t];
    __syncthreads();
    for (int d = 1; d < BNODES; d <<= 1) {
        int v = 0;
        if (t < BNODES && t >= d) v = lscan[t - d];
        __syncthreads();
        if (t < BNODES) lscan[t] += v;
        __syncthreads();
    }
    if (t < BNODES) {
        int node = nodeBase + t;
        if (node < N) {
            int c = lcnt[t];
            int o = s0 + lscan[t] - c;   // exclusive offset, absolute
            off[node] = o;
            lcnt[t] = o;                 // becomes the cursor
        }
    }
    __syncthreads();

    for (int i = s0 + t; i < s1; i += 256) {
        uint_t sd = stgSD[i];
        float2 kk = stgK[i];
        int pos = atomicAdd(&lcnt[(sd >> 16) & (BNODES - 1)], 1);
        srcU[pos] = (ushort_t)(sd & 0xFFFFu);
        kS[pos] = kk;
    }
}

// ---- conv1 + MLP1: half-wave per node; 16-lane group per edge -> h1 bf16 ----
__global__ __launch_bounds__(256) void conv1_mlp1_kernel(
        const float* __restrict__ x, const ushort_t* __restrict__ srcU,
        const float2* __restrict__ kS, const int* __restrict__ off,
        const float* __restrict__ W1, const float* __restrict__ b1,
        ushort_t* __restrict__ h1u, int N) {
    __shared__ float w[1024];
    __shared__ float bsh[32];
    for (int i = threadIdx.x; i < 1024; i += 256) w[i] = W1[i];
    if (threadIdx.x < 32) bsh[threadIdx.x] = b1[threadIdx.x];
    __syncthreads();

    int hw = threadIdx.x >> 5;        // half-wave 0..7 -> node
    int lane = threadIdx.x & 31;
    int node = blockIdx.x * 8 + hw;
    if (node >= N) return;

    int ch = lane & 15;
    int grp = lane >> 4;              // 0/1: edge parity
    int start = off[node];
    int deg = off[node + 1] - start;

    float a0 = 0.f, a1 = 0.f;
    int j = grp;
    for (; j + 6 < deg; j += 8) {     // edges j, j+2, j+4, j+6
        int p = start + j;
        int s0 = srcU[p], s1 = srcU[p + 2], s2 = srcU[p + 4], s3 = srcU[p + 6];
        float2 k0 = kS[p], k1 = kS[p + 2], k2 = kS[p + 4], k3 = kS[p + 6];
        float v0 = x[s0 * 16 + ch];
        float v1 = x[s1 * 16 + ch];
        float v2 = x[s2 * 16 + ch];
        float v3 = x[s3 * 16 + ch];
        a0 += k0.x * v0; a1 += k0.y * v0;
        a0 += k1.x * v1; a1 += k1.y * v1;
        a0 += k2.x * v2; a1 += k2.y * v2;
        a0 += k3.x * v3; a1 += k3.y * v3;
    }
    for (; j < deg; j += 2) {
        int p = start + j;
        int s = srcU[p];
        float2 kk = kS[p];
        float v = x[s * 16 + ch];
        a0 += kk.x * v; a1 += kk.y * v;
    }
    a0 += __shfl_xor(a0, 16, 32);
    a1 += __shfl_xor(a1, 16, 32);
    float acc = grp ? a1 : a0;

    float o = bsh[lane];
#pragma unroll
    for (int q = 0; q < 32; q++) o += __shfl(acc, q, 32) * w[q * 32 + lane];
    o = fmaxf(o, 0.f);
    float ss = o * o;
#pragma unroll
    for (int m = 16; m >= 1; m >>= 1) ss += __shfl_xor(ss, m, 32);
    h1u[node * 32 + lane] = f2bf(o / fmaxf(sqrtf(ss), EPSV));
}

// ---- conv2: wave/node; 8-lane group/edge; bf16 row gather -> h2 bf16 ----
__global__ __launch_bounds__(256) void conv2_gather_kernel(
        const ushort_t* __restrict__ h1u, const ushort_t* __restrict__ srcU,
        const float2* __restrict__ kS, const int* __restrict__ off,
        ushort_t* __restrict__ h2u, int N) {
    int wid = threadIdx.x >> 6;
    int lane = threadIdx.x & 63;
    int node = blockIdx.x * 4 + wid;
    if (node >= N) return;

    int grp = lane >> 3;              // 0..7: edge index mod 8
    int cq = lane & 7;                // channel quad: ch = cq*4..cq*4+3
    int start = off[node];
    int deg = off[node + 1] - start;

    float a00 = 0.f, a01 = 0.f, a02 = 0.f, a03 = 0.f;   // k0 * row[cq*4..]
    float a10 = 0.f, a11 = 0.f, a12 = 0.f, a13 = 0.f;   // k1 * row[cq*4..]
    int j = grp;
    for (; j + 8 < deg; j += 16) {    // edges j, j+8
        int p0 = start + j, p1 = p0 + 8;
        int s0 = srcU[p0], s1 = srcU[p1];
        float2 k0 = kS[p0], k1 = kS[p1];
        uint2 u0 = *(const uint2*)&h1u[s0 * 32 + cq * 4];
        uint2 u1 = *(const uint2*)&h1u[s1 * 32 + cq * 4];
        float v00 = unpk_lo(u0.x), v01 = unpk_hi(u0.x);
        float v02 = unpk_lo(u0.y), v03 = unpk_hi(u0.y);
        float v10 = unpk_lo(u1.x), v11 = unpk_hi(u1.x);
        float v12 = unpk_lo(u1.y), v13 = unpk_hi(u1.y);
        a00 += k0.x * v00; a01 += k0.x * v01; a02 += k0.x * v02; a03 += k0.x * v03;
        a10 += k0.y * v00; a11 += k0.y * v01; a12 += k0.y * v02; a13 += k0.y * v03;
        a00 += k1.x * v10; a01 += k1.x * v11; a02 += k1.x * v12; a03 += k1.x * v13;
        a10 += k1.y * v10; a11 += k1.y * v11; a12 += k1.y * v12; a13 += k1.y * v13;
    }
    for (; j < deg; j += 8) {
        int p = start + j;
        int s = srcU[p];
        float2 kk = kS[p];
        uint2 u = *(const uint2*)&h1u[s * 32 + cq * 4];
        float v0 = unpk_lo(u.x), v1 = unpk_hi(u.x);
        float v2 = unpk_lo(u.y), v3 = unpk_hi(u.y);
        a00 += kk.x * v0; a01 += kk.x * v1; a02 += kk.x * v2; a03 += kk.x * v3;
        a10 += kk.y * v0; a11 += kk.y * v1; a12 += kk.y * v2; a13 += kk.y * v3;
    }

#pragma unroll
    for (int m = 8; m < 64; m <<= 1) {
        a00 += __shfl_xor(a00, m, 64); a01 += __shfl_xor(a01, m, 64);
        a02 += __shfl_xor(a02, m, 64); a03 += __shfl_xor(a03, m, 64);
        a10 += __shfl_xor(a10, m, 64); a11 += __shfl_xor(a11, m, 64);
        a12 += __shfl_xor(a12, m, 64); a13 += __shfl_xor(a13, m, 64);
    }
    if (grp == 0) {
        uint2 o;
        o.x = (uint_t)f2bf(a00) | ((uint_t)f2bf(a01) << 16);
        o.y = (uint_t)f2bf(a02) | ((uint_t)f2bf(a03) << 16);
        *(uint2*)&h2u[(size_t)node * 64 + cq * 4] = o;
    } else if (grp == 1) {
        uint2 o;
        o.x = (uint_t)f2bf(a10) | ((uint_t)f2bf(a11) << 16);
        o.y = (uint_t)f2bf(a12) | ((uint_t)f2bf(a13) << 16);
        *(uint2*)&h2u[(size_t)node * 64 + 32 + cq * 4] = o;
    }
}

// ---- packW: W2a/W2b -> MFMA B-fragment order (bf16, coalesced uint4) ----
__global__ __launch_bounds__(256) void packW_kernel(
        const float* __restrict__ W2a, const float* __restrict__ W2b,
        uint4* __restrict__ wpkA, uint4* __restrict__ wpkB) {
    int gid = blockIdx.x * 256 + threadIdx.x;    // 0..2047
    if (gid < 1024) {
        int ct = gid >> 7, ks = (gid >> 6) & 1, l = gid & 63;
        int kb = l >> 4, m = l & 15;
        ushort_t us[8];
#pragma unroll
        for (int i = 0; i < 8; i++)
            us[i] = f2bf(W2a[(size_t)(ks * 32 + kb * 8 + i) * 128 + ct * 16 + m]);
        uint4 q;
        q.x = (uint_t)us[0] | ((uint_t)us[1] << 16);
        q.y = (uint_t)us[2] | ((uint_t)us[3] << 16);
        q.z = (uint_t)us[4] | ((uint_t)us[5] << 16);
        q.w = (uint_t)us[6] | ((uint_t)us[7] << 16);
        wpkA[gid] = q;
    } else {
        int e = gid - 1024;
        int ct = e >> 8, ks = (e >> 6) & 3, l = e & 63;
        int kb = l >> 4, m = l & 15;
        ushort_t us[8];
#pragma unroll
        for (int i = 0; i < 8; i++)
            us[i] = f2bf(W2b[(size_t)(ks * 32 + kb * 8 + i) * 64 + ct * 16 + m]);
        uint4 q;
        q.x = (uint_t)us[0] | ((uint_t)us[1] << 16);
        q.y = (uint_t)us[2] | ((uint_t)us[3] << 16);
        q.z = (uint_t)us[4] | ((uint_t)us[5] << 16);
        q.w = (uint_t)us[6] | ((uint_t)us[7] << 16);
        wpkB[e] = q;
    }
}

// ---- MLP2 via MFMA: 64 nodes/block, 4 waves x 16 nodes each ----
// h2u bf16 IS the A-fragment storage: lane m loads 16B = 8 bf16 directly.
__global__ __launch_bounds__(256) void mlp2_kernel(
        const ushort_t* __restrict__ h2u, const uint4* __restrict__ wpkA,
        const float* __restrict__ b2a, const uint4* __restrict__ wpkB,
        const float* __restrict__ b2b, float* __restrict__ out, int N) {
    __shared__ ushort_t hs[64 * 136];   // 17.4 KB

    int tid = threadIdx.x;
    int w = tid >> 6;          // wave 0..3 -> 16-node M-tile
    int l = tid & 63;
    int m = l & 15;
    int kb = l >> 4;           // 0..3
    int rowbase = w * 16;
    int n0 = blockIdx.x * 64;
    int anode = n0 + rowbase + m;      // A-side node for this lane
    bool alive = anode < N;

    // A-frags for GEMM1 (K=64 -> 2 steps): direct bf16 loads
    bf16x8 a1[2];
#pragma unroll
    for (int ks = 0; ks < 2; ks++) {
        union { uint4 q; bf16x8 v; } u;
        u.q = make_uint4(0, 0, 0, 0);
        if (alive)
            u.q = *(const uint4*)&h2u[(size_t)anode * 64 + ks * 32 + kb * 8];
        a1[ks] = u.v;
    }

    // GEMM1: 8 col-tiles x (2 MFMA) -> H[16][128] bf16 in LDS
#pragma unroll
    for (int ct = 0; ct < 8; ct++) {
        f32x4 acc = {0.f, 0.f, 0.f, 0.f};
        acc = __builtin_amdgcn_mfma_f32_16x16x32_bf16(
                  a1[0], ld_frag(&wpkA[(ct * 2 + 0) * 64 + l]), acc, 0, 0, 0);
        acc = __builtin_amdgcn_mfma_f32_16x16x32_bf16(
                  a1[1], ld_frag(&wpkA[(ct * 2 + 1) * 64 + l]), acc, 0, 0, 0);
        float bias = b2a[ct * 16 + m];
#pragma unroll
        for (int r = 0; r < 4; r++) {
            float hv = fmaxf(acc[r] + bias, 0.f);
            hs[(rowbase + kb * 4 + r) * 136 + ct * 16 + m] = f2bf(hv);
        }
    }
    __syncthreads();

    // A-frags for GEMM2 (K=128 -> 4 steps) from LDS (16B-aligned b128)
    bf16x8 a2[4];
#pragma unroll
    for (int ks = 0; ks < 4; ks++) {
        union { uint4 q; bf16x8 v; } u;
        u.q = *(const uint4*)&hs[(rowbase + m) * 136 + ks * 32 + kb * 8];
        a2[ks] = u.v;
    }

    // GEMM2: 4 col-tiles x (4 MFMA)
    f32x4 acc2[4];
#pragma unroll
    for (int ct = 0; ct < 4; ct++) {
        f32x4 acc = {0.f, 0.f, 0.f, 0.f};
#pragma unroll
        for (int ks = 0; ks < 4; ks++)
            acc = __builtin_amdgcn_mfma_f32_16x16x32_bf16(
                      a2[ks], ld_frag(&wpkB[(ct * 4 + ks) * 64 + l]), acc, 0, 0, 0);
        float bias = b2b[ct * 16 + m];
#pragma unroll
        for (int r = 0; r < 4; r++) acc2[ct][r] = acc[r] + bias;
    }

    // l2norm: lane holds rows kb*4+r, cols {ct*16+m}
#pragma unroll
    for (int r = 0; r < 4; r++) {
        float ss = acc2[0][r] * acc2[0][r] + acc2[1][r] * acc2[1][r] +
                   acc2[2][r] * acc2[2][r] + acc2[3][r] * acc2[3][r];
        ss += __shfl_xor(ss, 1, 16);
        ss += __shfl_xor(ss, 2, 16);
        ss += __shfl_xor(ss, 4, 16);
        ss += __shfl_xor(ss, 8, 16);
        float invn = 1.0f / fmaxf(sqrtf(ss), EPSV);
        int nrow = n0 + rowbase + kb * 4 + r;
        if (nrow < N) {
#pragma unroll
            for (int ct = 0; ct < 4; ct++)
                out[(size_t)nrow * 64 + ct * 16 + m] = acc2[ct][r] * invn;
        }
    }
}

extern "C" void kernel_launch(void* const* d_in, const int* in_sizes, int n_in,
                              void* d_out, int out_size, void* d_ws, size_t ws_size,
                              hipStream_t stream) {
    const float* x   = (const float*)d_in[0];
    const float* K   = (const float*)d_in[1];
    const int*   ei  = (const int*)d_in[2];
    const float* W1  = (const float*)d_in[3];
    const float* b1  = (const float*)d_in[4];
    const float* W2a = (const float*)d_in[5];
    const float* b2a = (const float*)d_in[6];
    const float* W2b = (const float*)d_in[7];
    const float* b2b = (const float*)d_in[8];
    float* out = (float*)d_out;

    const int D  = 16;
    const int NK = 2;
    const int N  = in_sizes[0] / D;        // 50000 (src,dst < 2^16)
    const int E  = in_sizes[1] / NK;       // 1600000
    const int nbuck = (N + BNODES - 1) >> BSH;  // 391 <= NB2
    const int HROWS = 256;                 // bhist blocks

    // workspace layout:
    //   region0 (overlaid in time):
    //     phase 1 (CSR build): stgK float2[E] | stgSD uint[E]   (E*12 B)
    //     phase 2+3:           h2u bf16[N*64] | h1u bf16[N*32]  (N*192 B)
    //   then: kS float2[E] | srcU ushort[E] | off[N+1] | cntmat[HROWS*NB2] |
    //         bbase[NB2+1] | bcur[NB2*BCPAD] | wpkA[1024] | wpkB[1024] uint4
    size_t region0 = (size_t)E * 12;
    size_t hbytes  = (size_t)N * 192;
    if (hbytes > region0) region0 = hbytes;

    ushort_t* h2u   = (ushort_t*)d_ws;
    ushort_t* h1u   = h2u + (size_t)N * 64;
    float2* stgK    = (float2*)d_ws;                  // phase 1
    uint_t* stgSD   = (uint_t*)(stgK + (size_t)E);    // phase 1
    float2* kS      = (float2*)((char*)d_ws + region0);
    ushort_t* srcU  = (ushort_t*)(kS + (size_t)E);
    int* off        = (int*)(((size_t)(srcU + (size_t)E) + 3) & ~(size_t)3);
    int* cntmat     = off + (N + 1);
    int* bbase      = cntmat + HROWS * NB2;
    int* bcur       = bbase + NB2 + 1;
    char* wp        = (char*)(bcur + NB2 * BCPAD);
    wp = (char*)(((size_t)wp + 15) & ~(size_t)15);
    uint4* wpkA     = (uint4*)wp;
    uint4* wpkB     = wpkA + 1024;

    packW_kernel<<<8, 256, 0, stream>>>(W2a, W2b, wpkA, wpkB);
    bhist_kernel<<<HROWS, 256, 0, stream>>>(ei, cntmat, E);
    bscan_kernel<<<1, NB2, 0, stream>>>(cntmat, bbase, bcur, off,
                                        nbuck, E, HROWS, N);

    int ablocks = (E + CHUNK - 1) / CHUNK;
    partA_kernel<<<ablocks, 256, 0, stream>>>(K, ei, bcur, stgSD, stgK, E);
    partB_kernel<<<nbuck, 256, 0, stream>>>(stgSD, stgK, bbase, off,
                                            srcU, kS, N);

    conv1_mlp1_kernel<<<(N + 7) / 8, 256, 0, stream>>>(x, srcU, kS, off,
                                                       W1, b1, h1u, N);
    conv2_gather_kernel<<<(N + 3) / 4, 256, 0, stream>>>(h1u, srcU, kS, off,
                                                         h2u, N);
    mlp2_kernel<<<(N + 63) / 64, 256, 0, stream>>>(h2u, wpkA, b2a, wpkB, b2b,
                                                   out, N);
}

// Round 18
// 158.830 us; speedup vs baseline: 1.1507x; 1.1250x over previous
//
#include <hip/hip_runtime.h>
#include <hip/hip_bf16.h>

// Pipeline (N=50000, E=1.6M, D=16, NK=2):
//   bhist: bucket (dst>>7) histogram -> cntmat
//   bscan: column-sum + scan -> bbase/bcur/off sentinel; also packs W (MFMA)
//   partA: bucket-partition edges into 8B records {src|dst<<16, bf16 k pair}
//          (CHUNK=4096, 512thr -> ~84B runs per bucket per block)
//   partB: per-128-node-bucket sort -> srcU(u16) + kU(bf16 pair) + off
//   conv1+mlp1: half-wave/node, 16-lane group/edge -> h1 bf16 (L2-fits)
//   conv2:      wave/node, 8-lane group/edge, bf16 row gather -> h2 bf16
//   mlp2:       MFMA path; h2 bf16 IS the A-fragment
//
// NOTE (round-7): NEVER atomicAdd on __shared__ float in hot loops (678us).
// NOTE (mlp2 R8-R14): vector-ALU mlp2 plateaued 45-56us; MFMA fixed it.
// NOTE (R17): conv2 was BW-bound on h1 gather; h1/h2 bf16 halves bytes.
// NOTE (R18): K bf16 through the whole CSR (one rounding, linear in convs)
//   cuts staging 19.2->12.8MB and edge stream 10->6B/edge.

#define EPSV 1e-12f
#define CHUNK 4096      // edges per partA block
#define NB2 512         // bucket slot array size (nbuck = ceil(N/128) = 391)
#define BSH 7           // bucket shift: 128 nodes per bucket
#define BNODES 128      // nodes per bucket
#define BCPAD 16        // bcur padding stride (ints)

typedef unsigned short ushort_t;
typedef unsigned int uint_t;
typedef __attribute__((ext_vector_type(8))) short bf16x8;
typedef __attribute__((ext_vector_type(4))) float f32x4;

// ---- per-block detection of int64 edge_index layout ----
__device__ __forceinline__ int detect_i64_block(const int* ei) {
    __shared__ int nz;
    if (threadIdx.x == 0) nz = 0;
    __syncthreads();
    int v = 0;
    for (int i = threadIdx.x; i < 1024; i += blockDim.x) v |= ei[2 * i + 1];
    if (v) atomicOr(&nz, 1);
    __syncthreads();
    return nz ? 0 : 1;     // 1 => int64 layout
}

__device__ __forceinline__ void load_edge(const int* ei, int e, int E, int flag,
                                          int& src, int& dst) {
    if (flag) {            // int64 storage: low words at even int32 indices
        src = ei[2 * e];
        dst = ei[2 * E + 2 * e];
    } else {               // int32 storage
        src = ei[e];
        dst = ei[E + e];
    }
}

// ---- bf16 helpers ----
__device__ __forceinline__ ushort_t f2bf(float f) {
    uint_t u = __float_as_uint(f);
    uint_t r = u + 0x7FFFu + ((u >> 16) & 1u);
    return (ushort_t)(r >> 16);
}
__device__ __forceinline__ uint_t pack2(float a, float b) {
    return (uint_t)f2bf(a) | ((uint_t)f2bf(b) << 16);
}
__device__ __forceinline__ float unpk_lo(uint_t u) {
    return __uint_as_float(u << 16);
}
__device__ __forceinline__ float unpk_hi(uint_t u) {
    return __uint_as_float(u & 0xFFFF0000u);
}
__device__ __forceinline__ bf16x8 ld_frag(const uint4* p) {
    union { uint4 q; bf16x8 v; } u;
    u.q = *p;
    return u.v;
}

// ---- bucket histogram: LDS-privatized, vectorized dst loads ----
__global__ __launch_bounds__(256) void bhist_kernel(
        const int* __restrict__ ei, int* __restrict__ cntmat, int E) {
    __shared__ int l[NB2];
    int flag = detect_i64_block(ei);
    for (int i = threadIdx.x; i < NB2; i += 256) l[i] = 0;
    __syncthreads();
    int stride = gridDim.x * 256;
    int gid = blockIdx.x * 256 + threadIdx.x;
    if ((E & 3) == 0) {
        if (flag) {
            const int4* p = (const int4*)(ei + 2 * (size_t)E);  // dst pairs
            int total = E >> 1;
            for (int i = gid; i < total; i += stride) {
                int4 v = p[i];
                atomicAdd(&l[v.x >> BSH], 1);
                atomicAdd(&l[v.z >> BSH], 1);
            }
        } else {
            const int4* p = (const int4*)(ei + (size_t)E);
            int total = E >> 2;
            for (int i = gid; i < total; i += stride) {
                int4 v = p[i];
                atomicAdd(&l[v.x >> BSH], 1);
                atomicAdd(&l[v.y >> BSH], 1);
                atomicAdd(&l[v.z >> BSH], 1);
                atomicAdd(&l[v.w >> BSH], 1);
            }
        }
    } else {
        for (int e = gid; e < E; e += stride) {
            int dst = flag ? ei[2 * (size_t)E + 2 * e] : ei[(size_t)E + e];
            atomicAdd(&l[dst >> BSH], 1);
        }
    }
    __syncthreads();
    for (int i = threadIdx.x; i < NB2; i += 256)
        cntmat[blockIdx.x * NB2 + i] = l[i];
}

// ---- bscan: column-sum + exclusive scan; ALSO packs W2a/W2b B-frags ----
__global__ __launch_bounds__(NB2) void bscan_kernel(
        const int* __restrict__ cntmat,
        int* __restrict__ bbase, int* __restrict__ bcur,
        int* __restrict__ off, int nbuck, int E, int nrows, int N,
        const float* __restrict__ W2a, const float* __restrict__ W2b,
        uint4* __restrict__ wpkA, uint4* __restrict__ wpkB) {
    // packW portion (independent work, 2048 items)
    for (int gid = threadIdx.x; gid < 2048; gid += NB2) {
        if (gid < 1024) {
            int ct = gid >> 7, ks = (gid >> 6) & 1, l = gid & 63;
            int kb = l >> 4, m = l & 15;
            ushort_t us[8];
#pragma unroll
            for (int i = 0; i < 8; i++)
                us[i] = f2bf(W2a[(size_t)(ks * 32 + kb * 8 + i) * 128 + ct * 16 + m]);
            uint4 q;
            q.x = (uint_t)us[0] | ((uint_t)us[1] << 16);
            q.y = (uint_t)us[2] | ((uint_t)us[3] << 16);
            q.z = (uint_t)us[4] | ((uint_t)us[5] << 16);
            q.w = (uint_t)us[6] | ((uint_t)us[7] << 16);
            wpkA[gid] = q;
        } else {
            int e = gid - 1024;
            int ct = e >> 8, ks = (e >> 6) & 3, l = e & 63;
            int kb = l >> 4, m = l & 15;
            ushort_t us[8];
#pragma unroll
            for (int i = 0; i < 8; i++)
                us[i] = f2bf(W2b[(size_t)(ks * 32 + kb * 8 + i) * 64 + ct * 16 + m]);
            uint4 q;
            q.x = (uint_t)us[0] | ((uint_t)us[1] << 16);
            q.y = (uint_t)us[2] | ((uint_t)us[3] << 16);
            q.z = (uint_t)us[4] | ((uint_t)us[5] << 16);
            q.w = (uint_t)us[6] | ((uint_t)us[7] << 16);
            wpkB[e] = q;
        }
    }

    __shared__ int s[NB2];
    int t = threadIdx.x;            // blockDim = NB2
    int c = 0;
    for (int i = 0; i < nrows; ++i) c += cntmat[i * NB2 + t];
    s[t] = c;
    __syncthreads();
    for (int d = 1; d < NB2; d <<= 1) {
        int v = (t >= d) ? s[t - d] : 0;
        __syncthreads();
        s[t] += v;
        __syncthreads();
    }
    int excl = s[t] - c;
    if (t < nbuck) { bbase[t] = excl; bcur[t * BCPAD] = excl; }
    if (t == 0) { bbase[nbuck] = E; off[N] = E; }
}

// ---- partA: bucket-partition; 8B records {sd, kbf}; 512thr, CHUNK=4096 ----
__global__ __launch_bounds__(512) void partA_kernel(
        const float* __restrict__ K, const int* __restrict__ ei,
        int* __restrict__ bcur, uint2* __restrict__ stg8, int E) {
    __shared__ int cnt[NB2];
    __shared__ int bexc[NB2];
    __shared__ int gbase[NB2];
    __shared__ int scanbuf[NB2];
    __shared__ uint2 stage[CHUNK];    // 32 KB

    int flag = detect_i64_block(ei);
    int e0 = blockIdx.x * CHUNK;
    int tot = min(CHUNK, E - e0);
    int t = threadIdx.x;

    cnt[t] = 0;                       // blockDim == NB2 == 512
    __syncthreads();

    int   myslot[CHUNK / 512];
    int   mybk[CHUNK / 512];
    uint2 myrec[CHUNK / 512];
#pragma unroll
    for (int it = 0; it < CHUNK / 512; ++it) {
        int e = e0 + it * 512 + t;
        mybk[it] = -1;
        if (e < E) {
            int src, dst;
            load_edge(ei, e, E, flag, src, dst);
            int bk = dst >> BSH;
            mybk[it] = bk;
            myrec[it].x = (uint_t)src | ((uint_t)dst << 16);
            myrec[it].y = pack2(K[e], K[E + e]);
            myslot[it] = atomicAdd(&cnt[bk], 1);
        }
    }
    __syncthreads();

    // scan NB2 buckets, one per thread
    int c = cnt[t];
    scanbuf[t] = c;
    __syncthreads();
    for (int d = 1; d < NB2; d <<= 1) {
        int v = (t >= d) ? scanbuf[t - d] : 0;
        __syncthreads();
        scanbuf[t] += v;
        __syncthreads();
    }
    int excl = scanbuf[t] - c;
    bexc[t] = excl;
    gbase[t] = c ? atomicAdd(&bcur[t * BCPAD], c) : 0;
    __syncthreads();

#pragma unroll
    for (int it = 0; it < CHUNK / 512; ++it) {
        if (mybk[it] >= 0) stage[bexc[mybk[it]] + myslot[it]] = myrec[it];
    }
    __syncthreads();

    for (int i = t; i < tot; i += 512) {
        uint2 r = stage[i];
        int bk = (int)(r.x >> 16) >> BSH;
        stg8[gbase[bk] + (i - bexc[bk])] = r;
    }
}

// ---- partB: one block per 128-node bucket; hist pass reads 8B/edge ----
__global__ __launch_bounds__(256) void partB_kernel(
        const uint2* __restrict__ stg8, const int* __restrict__ bbase,
        int* __restrict__ off, ushort_t* __restrict__ srcU,
        uint_t* __restrict__ kU, int N) {
    __shared__ int lcnt[BNODES];
    __shared__ int lscan[BNODES];

    int b = blockIdx.x;
    int nodeBase = b << BSH;
    int s0 = bbase[b];
    int s1 = bbase[b + 1];
    int t = threadIdx.x;

    if (t < BNODES) lcnt[t] = 0;
    __syncthreads();

    for (int i = s0 + t; i < s1; i += 256)
        atomicAdd(&lcnt[(stg8[i].x >> 16) & (BNODES - 1)], 1);
    __syncthreads();

    if (t < BNODES) lscan[t] = lcnt[t];
    __syncthreads();
    for (int d = 1; d < BNODES; d <<= 1) {
        int v = 0;
        if (t < BNODES && t >= d) v = lscan[t - d];
        __syncthreads();
        if (t < BNODES) lscan[t] += v;
        __syncthreads();
    }
    if (t < BNODES) {
        int node = nodeBase + t;
        if (node < N) {
            int c = lcnt[t];
            int o = s0 + lscan[t] - c;   // exclusive offset, absolute
            off[node] = o;
            lcnt[t] = o;                 // becomes the cursor
        }
    }
    __syncthreads();

    for (int i = s0 + t; i < s1; i += 256) {
        uint2 r = stg8[i];
        int pos = atomicAdd(&lcnt[(r.x >> 16) & (BNODES - 1)], 1);
        srcU[pos] = (ushort_t)(r.x & 0xFFFFu);
        kU[pos] = r.y;
    }
}

// ---- conv1 + MLP1: half-wave per node; 16-lane group per edge -> h1 bf16 ----
__global__ __launch_bounds__(256) void conv1_mlp1_kernel(
        const float* __restrict__ x, const ushort_t* __restrict__ srcU,
        const uint_t* __restrict__ kU, const int* __restrict__ off,
        const float* __restrict__ W1, const float* __restrict__ b1,
        ushort_t* __restrict__ h1u, int N) {
    __shared__ float w[1024];
    __shared__ float bsh[32];
    for (int i = threadIdx.x; i < 1024; i += 256) w[i] = W1[i];
    if (threadIdx.x < 32) bsh[threadIdx.x] = b1[threadIdx.x];
    __syncthreads();

    int hw = threadIdx.x >> 5;        // half-wave 0..7 -> node
    int lane = threadIdx.x & 31;
    int node = blockIdx.x * 8 + hw;
    if (node >= N) return;

    int ch = lane & 15;
    int grp = lane >> 4;              // 0/1: edge parity
    int start = off[node];
    int deg = off[node + 1] - start;

    float a0 = 0.f, a1 = 0.f;
    int j = grp;
    for (; j + 6 < deg; j += 8) {     // edges j, j+2, j+4, j+6
        int p = start + j;
        int s0 = srcU[p], s1 = srcU[p + 2], s2 = srcU[p + 4], s3 = srcU[p + 6];
        uint_t k0 = kU[p], k1 = kU[p + 2], k2 = kU[p + 4], k3 = kU[p + 6];
        float v0 = x[s0 * 16 + ch];
        float v1 = x[s1 * 16 + ch];
        float v2 = x[s2 * 16 + ch];
        float v3 = x[s3 * 16 + ch];
        a0 += unpk_lo(k0) * v0; a1 += unpk_hi(k0) * v0;
        a0 += unpk_lo(k1) * v1; a1 += unpk_hi(k1) * v1;
        a0 += unpk_lo(k2) * v2; a1 += unpk_hi(k2) * v2;
        a0 += unpk_lo(k3) * v3; a1 += unpk_hi(k3) * v3;
    }
    for (; j < deg; j += 2) {
        int p = start + j;
        int s = srcU[p];
        uint_t kk = kU[p];
        float v = x[s * 16 + ch];
        a0 += unpk_lo(kk) * v; a1 += unpk_hi(kk) * v;
    }
    a0 += __shfl_xor(a0, 16, 32);
    a1 += __shfl_xor(a1, 16, 32);
    float acc = grp ? a1 : a0;

    float o = bsh[lane];
#pragma unroll
    for (int q = 0; q < 32; q++) o += __shfl(acc, q, 32) * w[q * 32 + lane];
    o = fmaxf(o, 0.f);
    float ss = o * o;
#pragma unroll
    for (int m = 16; m >= 1; m >>= 1) ss += __shfl_xor(ss, m, 32);
    h1u[node * 32 + lane] = f2bf(o / fmaxf(sqrtf(ss), EPSV));
}

// ---- conv2: wave/node; 8-lane group/edge; bf16 row gather -> h2 bf16 ----
__global__ __launch_bounds__(256) void conv2_gather_kernel(
        const ushort_t* __restrict__ h1u, const ushort_t* __restrict__ srcU,
        const uint_t* __restrict__ kU, const int* __restrict__ off,
        ushort_t* __restrict__ h2u, int N) {
    int wid = threadIdx.x >> 6;
    int lane = threadIdx.x & 63;
    int node = blockIdx.x * 4 + wid;
    if (node >= N) return;

    int grp = lane >> 3;              // 0..7: edge index mod 8
    int cq = lane & 7;                // channel quad: ch = cq*4..cq*4+3
    int start = off[node];
    int deg = off[node + 1] - start;

    float a00 = 0.f, a01 = 0.f, a02 = 0.f, a03 = 0.f;   // k0 * row[cq*4..]
    float a10 = 0.f, a11 = 0.f, a12 = 0.f, a13 = 0.f;   // k1 * row[cq*4..]
    int j = grp;
    for (; j + 8 < deg; j += 16) {    // edges j, j+8
        int p0 = start + j, p1 = p0 + 8;
        int s0 = srcU[p0], s1 = srcU[p1];
        uint_t k0 = kU[p0], k1 = kU[p1];
        uint2 u0 = *(const uint2*)&h1u[s0 * 32 + cq * 4];
        uint2 u1 = *(const uint2*)&h1u[s1 * 32 + cq * 4];
        float k0l = unpk_lo(k0), k0h = unpk_hi(k0);
        float k1l = unpk_lo(k1), k1h = unpk_hi(k1);
        float v00 = unpk_lo(u0.x), v01 = unpk_hi(u0.x);
        float v02 = unpk_lo(u0.y), v03 = unpk_hi(u0.y);
        float v10 = unpk_lo(u1.x), v11 = unpk_hi(u1.x);
        float v12 = unpk_lo(u1.y), v13 = unpk_hi(u1.y);
        a00 += k0l * v00; a01 += k0l * v01; a02 += k0l * v02; a03 += k0l * v03;
        a10 += k0h * v00; a11 += k0h * v01; a12 += k0h * v02; a13 += k0h * v03;
        a00 += k1l * v10; a01 += k1l * v11; a02 += k1l * v12; a03 += k1l * v13;
        a10 += k1h * v10; a11 += k1h * v11; a12 += k1h * v12; a13 += k1h * v13;
    }
    for (; j < deg; j += 8) {
        int p = start + j;
        int s = srcU[p];
        uint_t kk = kU[p];
        uint2 u = *(const uint2*)&h1u[s * 32 + cq * 4];
        float kl = unpk_lo(kk), kh = unpk_hi(kk);
        float v0 = unpk_lo(u.x), v1 = unpk_hi(u.x);
        float v2 = unpk_lo(u.y), v3 = unpk_hi(u.y);
        a00 += kl * v0; a01 += kl * v1; a02 += kl * v2; a03 += kl * v3;
        a10 += kh * v0; a11 += kh * v1; a12 += kh * v2; a13 += kh * v3;
    }

#pragma unroll
    for (int m = 8; m < 64; m <<= 1) {
        a00 += __shfl_xor(a00, m, 64); a01 += __shfl_xor(a01, m, 64);
        a02 += __shfl_xor(a02, m, 64); a03 += __shfl_xor(a03, m, 64);
        a10 += __shfl_xor(a10, m, 64); a11 += __shfl_xor(a11, m, 64);
        a12 += __shfl_xor(a12, m, 64); a13 += __shfl_xor(a13, m, 64);
    }
    if (grp == 0) {
        uint2 o;
        o.x = (uint_t)f2bf(a00) | ((uint_t)f2bf(a01) << 16);
        o.y = (uint_t)f2bf(a02) | ((uint_t)f2bf(a03) << 16);
        *(uint2*)&h2u[(size_t)node * 64 + cq * 4] = o;
    } else if (grp == 1) {
        uint2 o;
        o.x = (uint_t)f2bf(a10) | ((uint_t)f2bf(a11) << 16);
        o.y = (uint_t)f2bf(a12) | ((uint_t)f2bf(a13) << 16);
        *(uint2*)&h2u[(size_t)node * 64 + 32 + cq * 4] = o;
    }
}

// ---- MLP2 via MFMA: 64 nodes/block, 4 waves x 16 nodes each ----
__global__ __launch_bounds__(256) void mlp2_kernel(
        const ushort_t* __restrict__ h2u, const uint4* __restrict__ wpkA,
        const float* __restrict__ b2a, const uint4* __restrict__ wpkB,
        const float* __restrict__ b2b, float* __restrict__ out, int N) {
    __shared__ ushort_t hs[64 * 136];   // 17.4 KB

    int tid = threadIdx.x;
    int w = tid >> 6;          // wave 0..3 -> 16-node M-tile
    int l = tid & 63;
    int m = l & 15;
    int kb = l >> 4;           // 0..3
    int rowbase = w * 16;
    int n0 = blockIdx.x * 64;
    int anode = n0 + rowbase + m;      // A-side node for this lane
    bool alive = anode < N;

    // A-frags for GEMM1 (K=64 -> 2 steps): direct bf16 loads
    bf16x8 a1[2];
#pragma unroll
    for (int ks = 0; ks < 2; ks++) {
        union { uint4 q; bf16x8 v; } u;
        u.q = make_uint4(0, 0, 0, 0);
        if (alive)
            u.q = *(const uint4*)&h2u[(size_t)anode * 64 + ks * 32 + kb * 8];
        a1[ks] = u.v;
    }

    // GEMM1: 8 col-tiles x (2 MFMA) -> H[16][128] bf16 in LDS
#pragma unroll
    for (int ct = 0; ct < 8; ct++) {
        f32x4 acc = {0.f, 0.f, 0.f, 0.f};
        acc = __builtin_amdgcn_mfma_f32_16x16x32_bf16(
                  a1[0], ld_frag(&wpkA[(ct * 2 + 0) * 64 + l]), acc, 0, 0, 0);
        acc = __builtin_amdgcn_mfma_f32_16x16x32_bf16(
                  a1[1], ld_frag(&wpkA[(ct * 2 + 1) * 64 + l]), acc, 0, 0, 0);
        float bias = b2a[ct * 16 + m];
#pragma unroll
        for (int r = 0; r < 4; r++) {
            float hv = fmaxf(acc[r] + bias, 0.f);
            hs[(rowbase + kb * 4 + r) * 136 + ct * 16 + m] = f2bf(hv);
        }
    }
    __syncthreads();

    // A-frags for GEMM2 (K=128 -> 4 steps) from LDS (16B-aligned b128)
    bf16x8 a2[4];
#pragma unroll
    for (int ks = 0; ks < 4; ks++) {
        union { uint4 q; bf16x8 v; } u;
        u.q = *(const uint4*)&hs[(rowbase + m) * 136 + ks * 32 + kb * 8];
        a2[ks] = u.v;
    }

    // GEMM2: 4 col-tiles x (4 MFMA)
    f32x4 acc2[4];
#pragma unroll
    for (int ct = 0; ct < 4; ct++) {
        f32x4 acc = {0.f, 0.f, 0.f, 0.f};
#pragma unroll
        for (int ks = 0; ks < 4; ks++)
            acc = __builtin_amdgcn_mfma_f32_16x16x32_bf16(
                      a2[ks], ld_frag(&wpkB[(ct * 4 + ks) * 64 + l]), acc, 0, 0, 0);
        float bias = b2b[ct * 16 + m];
#pragma unroll
        for (int r = 0; r < 4; r++) acc2[ct][r] = acc[r] + bias;
    }

    // l2norm: lane holds rows kb*4+r, cols {ct*16+m}
#pragma unroll
    for (int r = 0; r < 4; r++) {
        float ss = acc2[0][r] * acc2[0][r] + acc2[1][r] * acc2[1][r] +
                   acc2[2][r] * acc2[2][r] + acc2[3][r] * acc2[3][r];
        ss += __shfl_xor(ss, 1, 16);
        ss += __shfl_xor(ss, 2, 16);
        ss += __shfl_xor(ss, 4, 16);
        ss += __shfl_xor(ss, 8, 16);
        float invn = 1.0f / fmaxf(sqrtf(ss), EPSV);
        int nrow = n0 + rowbase + kb * 4 + r;
        if (nrow < N) {
#pragma unroll
            for (int ct = 0; ct < 4; ct++)
                out[(size_t)nrow * 64 + ct * 16 + m] = acc2[ct][r] * invn;
        }
    }
}

extern "C" void kernel_launch(void* const* d_in, const int* in_sizes, int n_in,
                              void* d_out, int out_size, void* d_ws, size_t ws_size,
                              hipStream_t stream) {
    const float* x   = (const float*)d_in[0];
    const float* K   = (const float*)d_in[1];
    const int*   ei  = (const int*)d_in[2];
    const float* W1  = (const float*)d_in[3];
    const float* b1  = (const float*)d_in[4];
    const float* W2a = (const float*)d_in[5];
    const float* b2a = (const float*)d_in[6];
    const float* W2b = (const float*)d_in[7];
    const float* b2b = (const float*)d_in[8];
    float* out = (float*)d_out;

    const int D  = 16;
    const int NK = 2;
    const int N  = in_sizes[0] / D;        // 50000 (src,dst < 2^16)
    const int E  = in_sizes[1] / NK;       // 1600000
    const int nbuck = (N + BNODES - 1) >> BSH;  // 391 <= NB2
    const int HROWS = 256;                 // bhist blocks

    // workspace layout:
    //   region0 (overlaid in time):
    //     phase 1 (CSR build): stg8 uint2[E]                    (E*8 B)
    //     phase 2+3:           h2u bf16[N*64] | h1u bf16[N*32]  (N*192 B)
    //   then: kU uint[E] | srcU ushort[E] | off[N+1] | cntmat[HROWS*NB2] |
    //         bbase[NB2+1] | bcur[NB2*BCPAD] | wpkA[1024] | wpkB[1024] uint4
    size_t region0 = (size_t)E * 8;
    size_t hbytes  = (size_t)N * 192;
    if (hbytes > region0) region0 = hbytes;

    ushort_t* h2u   = (ushort_t*)d_ws;
    ushort_t* h1u   = h2u + (size_t)N * 64;
    uint2* stg8     = (uint2*)d_ws;                   // phase 1
    uint_t* kU      = (uint_t*)((char*)d_ws + region0);
    ushort_t* srcU  = (ushort_t*)(kU + (size_t)E);
    int* off        = (int*)(((size_t)(srcU + (size_t)E) + 3) & ~(size_t)3);
    int* cntmat     = off + (N + 1);
    int* bbase      = cntmat + HROWS * NB2;
    int* bcur       = bbase + NB2 + 1;
    char* wp        = (char*)(bcur + NB2 * BCPAD);
    wp = (char*)(((size_t)wp + 15) & ~(size_t)15);
    uint4* wpkA     = (uint4*)wp;
    uint4* wpkB     = wpkA + 1024;

    bhist_kernel<<<HROWS, 256, 0, stream>>>(ei, cntmat, E);
    bscan_kernel<<<1, NB2, 0, stream>>>(cntmat, bbase, bcur, off,
                                        nbuck, E, HROWS, N,
                                        W2a, W2b, wpkA, wpkB);

    int ablocks = (E + CHUNK - 1) / CHUNK;
    partA_kernel<<<ablocks, 512, 0, stream>>>(K, ei, bcur, stg8, E);
    partB_kernel<<<nbuck, 256, 0, stream>>>(stg8, bbase, off, srcU, kU, N);

    conv1_mlp1_kernel<<<(N + 7) / 8, 256, 0, stream>>>(x, srcU, kU, off,
                                                       W1, b1, h1u, N);
    conv2_gather_kernel<<<(N + 3) / 4, 256, 0, stream>>>(h1u, srcU, kU, off,
                                                         h2u, N);
    mlp2_kernel<<<(N + 63) / 64, 256, 0, stream>>>(h2u, wpkA, b2a, wpkB, b2b,
                                                   out, N);
}

// Round 19
// 135.373 us; speedup vs baseline: 1.3501x; 1.1733x over previous
//
#include <hip/hip_runtime.h>
#include <hip/hip_bf16.h>

// Pipeline (N=50000, E=1.6M, D=16, NK=2):
//   bhist: bucket (dst>>7) histogram, LDS-private -> global atomic bcount[512]
//   bscan: scan 512 bucket counts (tiny) -> bbase/bcur/off sentinel; packs W
//   partA: bucket-partition edges into 8B records {src|dst<<16, bf16 k pair}
//   partB: per-128-node-bucket sort -> srcU(u16) + kU(bf16 pair) + off
//   conv1+mlp1: half-wave/node, 16-lane group/edge -> h1 bf16 (L2-fits)
//   conv2:      wave/node, 8-lane group/edge, bf16 row gather -> h2 bf16
//   mlp2:       MFMA path; h2 bf16 IS the A-fragment
//
// NOTE (round-7): NEVER atomicAdd on __shared__ float in hot loops (678us).
// NOTE (mlp2 R8-R14): vector-ALU mlp2 plateaued 45-56us; MFMA fixed it.
// NOTE (R18): bscan's single-block 256-row column-sum was 44us (0.08% occ,
//   dependent L2 loads). Fix: bhist atomics straight into bcount[512].

#define EPSV 1e-12f
#define CHUNK 4096      // edges per partA block
#define NB2 512         // bucket slot array size (nbuck = ceil(N/128) = 391)
#define BSH 7           // bucket shift: 128 nodes per bucket
#define BNODES 128      // nodes per bucket
#define BCPAD 16        // bcur padding stride (ints)

typedef unsigned short ushort_t;
typedef unsigned int uint_t;
typedef __attribute__((ext_vector_type(8))) short bf16x8;
typedef __attribute__((ext_vector_type(4))) float f32x4;

// ---- per-block detection of int64 edge_index layout ----
__device__ __forceinline__ int detect_i64_block(const int* ei) {
    __shared__ int nz;
    if (threadIdx.x == 0) nz = 0;
    __syncthreads();
    int v = 0;
    for (int i = threadIdx.x; i < 1024; i += blockDim.x) v |= ei[2 * i + 1];
    if (v) atomicOr(&nz, 1);
    __syncthreads();
    return nz ? 0 : 1;     // 1 => int64 layout
}

__device__ __forceinline__ void load_edge(const int* ei, int e, int E, int flag,
                                          int& src, int& dst) {
    if (flag) {            // int64 storage: low words at even int32 indices
        src = ei[2 * e];
        dst = ei[2 * E + 2 * e];
    } else {               // int32 storage
        src = ei[e];
        dst = ei[E + e];
    }
}

// ---- bf16 helpers ----
__device__ __forceinline__ ushort_t f2bf(float f) {
    uint_t u = __float_as_uint(f);
    uint_t r = u + 0x7FFFu + ((u >> 16) & 1u);
    return (ushort_t)(r >> 16);
}
__device__ __forceinline__ uint_t pack2(float a, float b) {
    return (uint_t)f2bf(a) | ((uint_t)f2bf(b) << 16);
}
__device__ __forceinline__ float unpk_lo(uint_t u) {
    return __uint_as_float(u << 16);
}
__device__ __forceinline__ float unpk_hi(uint_t u) {
    return __uint_as_float(u & 0xFFFF0000u);
}
__device__ __forceinline__ bf16x8 ld_frag(const uint4* p) {
    union { uint4 q; bf16x8 v; } u;
    u.q = *p;
    return u.v;
}

// ---- bucket histogram: LDS-private, flush to global bcount via atomics ----
__global__ __launch_bounds__(256) void bhist_kernel(
        const int* __restrict__ ei, int* __restrict__ bcount, int E) {
    __shared__ int l[NB2];
    int flag = detect_i64_block(ei);
    for (int i = threadIdx.x; i < NB2; i += 256) l[i] = 0;
    __syncthreads();
    int stride = gridDim.x * 256;
    int gid = blockIdx.x * 256 + threadIdx.x;
    if ((E & 3) == 0) {
        if (flag) {
            const int4* p = (const int4*)(ei + 2 * (size_t)E);  // dst pairs
            int total = E >> 1;
            for (int i = gid; i < total; i += stride) {
                int4 v = p[i];
                atomicAdd(&l[v.x >> BSH], 1);
                atomicAdd(&l[v.z >> BSH], 1);
            }
        } else {
            const int4* p = (const int4*)(ei + (size_t)E);
            int total = E >> 2;
            for (int i = gid; i < total; i += stride) {
                int4 v = p[i];
                atomicAdd(&l[v.x >> BSH], 1);
                atomicAdd(&l[v.y >> BSH], 1);
                atomicAdd(&l[v.z >> BSH], 1);
                atomicAdd(&l[v.w >> BSH], 1);
            }
        }
    } else {
        for (int e = gid; e < E; e += stride) {
            int dst = flag ? ei[2 * (size_t)E + 2 * e] : ei[(size_t)E + e];
            atomicAdd(&l[dst >> BSH], 1);
        }
    }
    __syncthreads();
    for (int i = threadIdx.x; i < NB2; i += 256) {
        int c = l[i];
        if (c) atomicAdd(&bcount[i], c);
    }
}

// ---- bscan: scan 512 bucket counts; ALSO packs W2a/W2b B-frags ----
__global__ __launch_bounds__(NB2) void bscan_kernel(
        const int* __restrict__ bcount,
        int* __restrict__ bbase, int* __restrict__ bcur,
        int* __restrict__ off, int nbuck, int E, int N,
        const float* __restrict__ W2a, const float* __restrict__ W2b,
        uint4* __restrict__ wpkA, uint4* __restrict__ wpkB) {
    // packW portion (independent work, 2048 items)
    for (int gid = threadIdx.x; gid < 2048; gid += NB2) {
        if (gid < 1024) {
            int ct = gid >> 7, ks = (gid >> 6) & 1, l = gid & 63;
            int kb = l >> 4, m = l & 15;
            ushort_t us[8];
#pragma unroll
            for (int i = 0; i < 8; i++)
                us[i] = f2bf(W2a[(size_t)(ks * 32 + kb * 8 + i) * 128 + ct * 16 + m]);
            uint4 q;
            q.x = (uint_t)us[0] | ((uint_t)us[1] << 16);
            q.y = (uint_t)us[2] | ((uint_t)us[3] << 16);
            q.z = (uint_t)us[4] | ((uint_t)us[5] << 16);
            q.w = (uint_t)us[6] | ((uint_t)us[7] << 16);
            wpkA[gid] = q;
        } else {
            int e = gid - 1024;
            int ct = e >> 8, ks = (e >> 6) & 3, l = e & 63;
            int kb = l >> 4, m = l & 15;
            ushort_t us[8];
#pragma unroll
            for (int i = 0; i < 8; i++)
                us[i] = f2bf(W2b[(size_t)(ks * 32 + kb * 8 + i) * 64 + ct * 16 + m]);
            uint4 q;
            q.x = (uint_t)us[0] | ((uint_t)us[1] << 16);
            q.y = (uint_t)us[2] | ((uint_t)us[3] << 16);
            q.z = (uint_t)us[4] | ((uint_t)us[5] << 16);
            q.w = (uint_t)us[6] | ((uint_t)us[7] << 16);
            wpkB[e] = q;
        }
    }

    __shared__ int s[NB2];
    int t = threadIdx.x;            // blockDim = NB2
    int c = bcount[t];
    s[t] = c;
    __syncthreads();
    for (int d = 1; d < NB2; d <<= 1) {
        int v = (t >= d) ? s[t - d] : 0;
        __syncthreads();
        s[t] += v;
        __syncthreads();
    }
    int excl = s[t] - c;
    if (t < nbuck) { bbase[t] = excl; bcur[t * BCPAD] = excl; }
    if (t == 0) { bbase[nbuck] = E; off[N] = E; }
}

// ---- partA: bucket-partition; 8B records {sd, kbf}; 512thr, CHUNK=4096 ----
__global__ __launch_bounds__(512) void partA_kernel(
        const float* __restrict__ K, const int* __restrict__ ei,
        int* __restrict__ bcur, uint2* __restrict__ stg8, int E) {
    __shared__ int cnt[NB2];
    __shared__ int bexc[NB2];
    __shared__ int gbase[NB2];
    __shared__ int scanbuf[NB2];
    __shared__ uint2 stage[CHUNK];    // 32 KB

    int flag = detect_i64_block(ei);
    int e0 = blockIdx.x * CHUNK;
    int tot = min(CHUNK, E - e0);
    int t = threadIdx.x;

    cnt[t] = 0;                       // blockDim == NB2 == 512
    __syncthreads();

    int   myslot[CHUNK / 512];
    int   mybk[CHUNK / 512];
    uint2 myrec[CHUNK / 512];
#pragma unroll
    for (int it = 0; it < CHUNK / 512; ++it) {
        int e = e0 + it * 512 + t;
        mybk[it] = -1;
        if (e < E) {
            int src, dst;
            load_edge(ei, e, E, flag, src, dst);
            int bk = dst >> BSH;
            mybk[it] = bk;
            myrec[it].x = (uint_t)src | ((uint_t)dst << 16);
            myrec[it].y = pack2(K[e], K[E + e]);
            myslot[it] = atomicAdd(&cnt[bk], 1);
        }
    }
    __syncthreads();

    // scan NB2 buckets, one per thread
    int c = cnt[t];
    scanbuf[t] = c;
    __syncthreads();
    for (int d = 1; d < NB2; d <<= 1) {
        int v = (t >= d) ? scanbuf[t - d] : 0;
        __syncthreads();
        scanbuf[t] += v;
        __syncthreads();
    }
    int excl = scanbuf[t] - c;
    bexc[t] = excl;
    gbase[t] = c ? atomicAdd(&bcur[t * BCPAD], c) : 0;
    __syncthreads();

#pragma unroll
    for (int it = 0; it < CHUNK / 512; ++it) {
        if (mybk[it] >= 0) stage[bexc[mybk[it]] + myslot[it]] = myrec[it];
    }
    __syncthreads();

    for (int i = t; i < tot; i += 512) {
        uint2 r = stage[i];
        int bk = (int)(r.x >> 16) >> BSH;
        stg8[gbase[bk] + (i - bexc[bk])] = r;
    }
}

// ---- partB: one block per 128-node bucket; hist pass reads 8B/edge ----
__global__ __launch_bounds__(256) void partB_kernel(
        const uint2* __restrict__ stg8, const int* __restrict__ bbase,
        int* __restrict__ off, ushort_t* __restrict__ srcU,
        uint_t* __restrict__ kU, int N) {
    __shared__ int lcnt[BNODES];
    __shared__ int lscan[BNODES];

    int b = blockIdx.x;
    int nodeBase = b << BSH;
    int s0 = bbase[b];
    int s1 = bbase[b + 1];
    int t = threadIdx.x;

    if (t < BNODES) lcnt[t] = 0;
    __syncthreads();

    for (int i = s0 + t; i < s1; i += 256)
        atomicAdd(&lcnt[(stg8[i].x >> 16) & (BNODES - 1)], 1);
    __syncthreads();

    if (t < BNODES) lscan[t] = lcnt[t];
    __syncthreads();
    for (int d = 1; d < BNODES; d <<= 1) {
        int v = 0;
        if (t < BNODES && t >= d) v = lscan[t - d];
        __syncthreads();
        if (t < BNODES) lscan[t] += v;
        __syncthreads();
    }
    if (t < BNODES) {
        int node = nodeBase + t;
        if (node < N) {
            int c = lcnt[t];
            int o = s0 + lscan[t] - c;   // exclusive offset, absolute
            off[node] = o;
            lcnt[t] = o;                 // becomes the cursor
        }
    }
    __syncthreads();

    for (int i = s0 + t; i < s1; i += 256) {
        uint2 r = stg8[i];
        int pos = atomicAdd(&lcnt[(r.x >> 16) & (BNODES - 1)], 1);
        srcU[pos] = (ushort_t)(r.x & 0xFFFFu);
        kU[pos] = r.y;
    }
}

// ---- conv1 + MLP1: half-wave per node; 16-lane group per edge -> h1 bf16 ----
__global__ __launch_bounds__(256) void conv1_mlp1_kernel(
        const float* __restrict__ x, const ushort_t* __restrict__ srcU,
        const uint_t* __restrict__ kU, const int* __restrict__ off,
        const float* __restrict__ W1, const float* __restrict__ b1,
        ushort_t* __restrict__ h1u, int N) {
    __shared__ float w[1024];
    __shared__ float bsh[32];
    for (int i = threadIdx.x; i < 1024; i += 256) w[i] = W1[i];
    if (threadIdx.x < 32) bsh[threadIdx.x] = b1[threadIdx.x];
    __syncthreads();

    int hw = threadIdx.x >> 5;        // half-wave 0..7 -> node
    int lane = threadIdx.x & 31;
    int node = blockIdx.x * 8 + hw;
    if (node >= N) return;

    int ch = lane & 15;
    int grp = lane >> 4;              // 0/1: edge parity
    int start = off[node];
    int deg = off[node + 1] - start;

    float a0 = 0.f, a1 = 0.f;
    int j = grp;
    for (; j + 6 < deg; j += 8) {     // edges j, j+2, j+4, j+6
        int p = start + j;
        int s0 = srcU[p], s1 = srcU[p + 2], s2 = srcU[p + 4], s3 = srcU[p + 6];
        uint_t k0 = kU[p], k1 = kU[p + 2], k2 = kU[p + 4], k3 = kU[p + 6];
        float v0 = x[s0 * 16 + ch];
        float v1 = x[s1 * 16 + ch];
        float v2 = x[s2 * 16 + ch];
        float v3 = x[s3 * 16 + ch];
        a0 += unpk_lo(k0) * v0; a1 += unpk_hi(k0) * v0;
        a0 += unpk_lo(k1) * v1; a1 += unpk_hi(k1) * v1;
        a0 += unpk_lo(k2) * v2; a1 += unpk_hi(k2) * v2;
        a0 += unpk_lo(k3) * v3; a1 += unpk_hi(k3) * v3;
    }
    for (; j < deg; j += 2) {
        int p = start + j;
        int s = srcU[p];
        uint_t kk = kU[p];
        float v = x[s * 16 + ch];
        a0 += unpk_lo(kk) * v; a1 += unpk_hi(kk) * v;
    }
    a0 += __shfl_xor(a0, 16, 32);
    a1 += __shfl_xor(a1, 16, 32);
    float acc = grp ? a1 : a0;

    float o = bsh[lane];
#pragma unroll
    for (int q = 0; q < 32; q++) o += __shfl(acc, q, 32) * w[q * 32 + lane];
    o = fmaxf(o, 0.f);
    float ss = o * o;
#pragma unroll
    for (int m = 16; m >= 1; m >>= 1) ss += __shfl_xor(ss, m, 32);
    h1u[node * 32 + lane] = f2bf(o / fmaxf(sqrtf(ss), EPSV));
}

// ---- conv2: wave/node; 8-lane group/edge; bf16 row gather -> h2 bf16 ----
__global__ __launch_bounds__(256) void conv2_gather_kernel(
        const ushort_t* __restrict__ h1u, const ushort_t* __restrict__ srcU,
        const uint_t* __restrict__ kU, const int* __restrict__ off,
        ushort_t* __restrict__ h2u, int N) {
    int wid = threadIdx.x >> 6;
    int lane = threadIdx.x & 63;
    int node = blockIdx.x * 4 + wid;
    if (node >= N) return;

    int grp = lane >> 3;              // 0..7: edge index mod 8
    int cq = lane & 7;                // channel quad: ch = cq*4..cq*4+3
    int start = off[node];
    int deg = off[node + 1] - start;

    float a00 = 0.f, a01 = 0.f, a02 = 0.f, a03 = 0.f;   // k0 * row[cq*4..]
    float a10 = 0.f, a11 = 0.f, a12 = 0.f, a13 = 0.f;   // k1 * row[cq*4..]
    int j = grp;
    for (; j + 8 < deg; j += 16) {    // edges j, j+8
        int p0 = start + j, p1 = p0 + 8;
        int s0 = srcU[p0], s1 = srcU[p1];
        uint_t k0 = kU[p0], k1 = kU[p1];
        uint2 u0 = *(const uint2*)&h1u[s0 * 32 + cq * 4];
        uint2 u1 = *(const uint2*)&h1u[s1 * 32 + cq * 4];
        float k0l = unpk_lo(k0), k0h = unpk_hi(k0);
        float k1l = unpk_lo(k1), k1h = unpk_hi(k1);
        float v00 = unpk_lo(u0.x), v01 = unpk_hi(u0.x);
        float v02 = unpk_lo(u0.y), v03 = unpk_hi(u0.y);
        float v10 = unpk_lo(u1.x), v11 = unpk_hi(u1.x);
        float v12 = unpk_lo(u1.y), v13 = unpk_hi(u1.y);
        a00 += k0l * v00; a01 += k0l * v01; a02 += k0l * v02; a03 += k0l * v03;
        a10 += k0h * v00; a11 += k0h * v01; a12 += k0h * v02; a13 += k0h * v03;
        a00 += k1l * v10; a01 += k1l * v11; a02 += k1l * v12; a03 += k1l * v13;
        a10 += k1h * v10; a11 += k1h * v11; a12 += k1h * v12; a13 += k1h * v13;
    }
    for (; j < deg; j += 8) {
        int p = start + j;
        int s = srcU[p];
        uint_t kk = kU[p];
        uint2 u = *(const uint2*)&h1u[s * 32 + cq * 4];
        float kl = unpk_lo(kk), kh = unpk_hi(kk);
        float v0 = unpk_lo(u.x), v1 = unpk_hi(u.x);
        float v2 = unpk_lo(u.y), v3 = unpk_hi(u.y);
        a00 += kl * v0; a01 += kl * v1; a02 += kl * v2; a03 += kl * v3;
        a10 += kh * v0; a11 += kh * v1; a12 += kh * v2; a13 += kh * v3;
    }

#pragma unroll
    for (int m = 8; m < 64; m <<= 1) {
        a00 += __shfl_xor(a00, m, 64); a01 += __shfl_xor(a01, m, 64);
        a02 += __shfl_xor(a02, m, 64); a03 += __shfl_xor(a03, m, 64);
        a10 += __shfl_xor(a10, m, 64); a11 += __shfl_xor(a11, m, 64);
        a12 += __shfl_xor(a12, m, 64); a13 += __shfl_xor(a13, m, 64);
    }
    if (grp == 0) {
        uint2 o;
        o.x = (uint_t)f2bf(a00) | ((uint_t)f2bf(a01) << 16);
        o.y = (uint_t)f2bf(a02) | ((uint_t)f2bf(a03) << 16);
        *(uint2*)&h2u[(size_t)node * 64 + cq * 4] = o;
    } else if (grp == 1) {
        uint2 o;
        o.x = (uint_t)f2bf(a10) | ((uint_t)f2bf(a11) << 16);
        o.y = (uint_t)f2bf(a12) | ((uint_t)f2bf(a13) << 16);
        *(uint2*)&h2u[(size_t)node * 64 + 32 + cq * 4] = o;
    }
}

// ---- MLP2 via MFMA: 64 nodes/block, 4 waves x 16 nodes each ----
__global__ __launch_bounds__(256) void mlp2_kernel(
        const ushort_t* __restrict__ h2u, const uint4* __restrict__ wpkA,
        const float* __restrict__ b2a, const uint4* __restrict__ wpkB,
        const float* __restrict__ b2b, float* __restrict__ out, int N) {
    __shared__ ushort_t hs[64 * 136];   // 17.4 KB

    int tid = threadIdx.x;
    int w = tid >> 6;          // wave 0..3 -> 16-node M-tile
    int l = tid & 63;
    int m = l & 15;
    int kb = l >> 4;           // 0..3
    int rowbase = w * 16;
    int n0 = blockIdx.x * 64;
    int anode = n0 + rowbase + m;      // A-side node for this lane
    bool alive = anode < N;

    // A-frags for GEMM1 (K=64 -> 2 steps): direct bf16 loads
    bf16x8 a1[2];
#pragma unroll
    for (int ks = 0; ks < 2; ks++) {
        union { uint4 q; bf16x8 v; } u;
        u.q = make_uint4(0, 0, 0, 0);
        if (alive)
            u.q = *(const uint4*)&h2u[(size_t)anode * 64 + ks * 32 + kb * 8];
        a1[ks] = u.v;
    }

    // GEMM1: 8 col-tiles x (2 MFMA) -> H[16][128] bf16 in LDS
#pragma unroll
    for (int ct = 0; ct < 8; ct++) {
        f32x4 acc = {0.f, 0.f, 0.f, 0.f};
        acc = __builtin_amdgcn_mfma_f32_16x16x32_bf16(
                  a1[0], ld_frag(&wpkA[(ct * 2 + 0) * 64 + l]), acc, 0, 0, 0);
        acc = __builtin_amdgcn_mfma_f32_16x16x32_bf16(
                  a1[1], ld_frag(&wpkA[(ct * 2 + 1) * 64 + l]), acc, 0, 0, 0);
        float bias = b2a[ct * 16 + m];
#pragma unroll
        for (int r = 0; r < 4; r++) {
            float hv = fmaxf(acc[r] + bias, 0.f);
            hs[(rowbase + kb * 4 + r) * 136 + ct * 16 + m] = f2bf(hv);
        }
    }
    __syncthreads();

    // A-frags for GEMM2 (K=128 -> 4 steps) from LDS (16B-aligned b128)
    bf16x8 a2[4];
#pragma unroll
    for (int ks = 0; ks < 4; ks++) {
        union { uint4 q; bf16x8 v; } u;
        u.q = *(const uint4*)&hs[(rowbase + m) * 136 + ks * 32 + kb * 8];
        a2[ks] = u.v;
    }

    // GEMM2: 4 col-tiles x (4 MFMA)
    f32x4 acc2[4];
#pragma unroll
    for (int ct = 0; ct < 4; ct++) {
        f32x4 acc = {0.f, 0.f, 0.f, 0.f};
#pragma unroll
        for (int ks = 0; ks < 4; ks++)
            acc = __builtin_amdgcn_mfma_f32_16x16x32_bf16(
                      a2[ks], ld_frag(&wpkB[(ct * 4 + ks) * 64 + l]), acc, 0, 0, 0);
        float bias = b2b[ct * 16 + m];
#pragma unroll
        for (int r = 0; r < 4; r++) acc2[ct][r] = acc[r] + bias;
    }

    // l2norm: lane holds rows kb*4+r, cols {ct*16+m}
#pragma unroll
    for (int r = 0; r < 4; r++) {
        float ss = acc2[0][r] * acc2[0][r] + acc2[1][r] * acc2[1][r] +
                   acc2[2][r] * acc2[2][r] + acc2[3][r] * acc2[3][r];
        ss += __shfl_xor(ss, 1, 16);
        ss += __shfl_xor(ss, 2, 16);
        ss += __shfl_xor(ss, 4, 16);
        ss += __shfl_xor(ss, 8, 16);
        float invn = 1.0f / fmaxf(sqrtf(ss), EPSV);
        int nrow = n0 + rowbase + kb * 4 + r;
        if (nrow < N) {
#pragma unroll
            for (int ct = 0; ct < 4; ct++)
                out[(size_t)nrow * 64 + ct * 16 + m] = acc2[ct][r] * invn;
        }
    }
}

extern "C" void kernel_launch(void* const* d_in, const int* in_sizes, int n_in,
                              void* d_out, int out_size, void* d_ws, size_t ws_size,
                              hipStream_t stream) {
    const float* x   = (const float*)d_in[0];
    const float* K   = (const float*)d_in[1];
    const int*   ei  = (const int*)d_in[2];
    const float* W1  = (const float*)d_in[3];
    const float* b1  = (const float*)d_in[4];
    const float* W2a = (const float*)d_in[5];
    const float* b2a = (const float*)d_in[6];
    const float* W2b = (const float*)d_in[7];
    const float* b2b = (const float*)d_in[8];
    float* out = (float*)d_out;

    const int D  = 16;
    const int NK = 2;
    const int N  = in_sizes[0] / D;        // 50000 (src,dst < 2^16)
    const int E  = in_sizes[1] / NK;       // 1600000
    const int nbuck = (N + BNODES - 1) >> BSH;  // 391 <= NB2
    const int HROWS = 256;                 // bhist blocks

    // workspace layout:
    //   region0 (overlaid in time):
    //     phase 1 (CSR build): stg8 uint2[E]                    (E*8 B)
    //     phase 2+3:           h2u bf16[N*64] | h1u bf16[N*32]  (N*192 B)
    //   then: kU uint[E] | srcU ushort[E] | off[N+1] | bcount[NB2] |
    //         bbase[NB2+1] | bcur[NB2*BCPAD] | wpkA[1024] | wpkB[1024] uint4
    size_t region0 = (size_t)E * 8;
    size_t hbytes  = (size_t)N * 192;
    if (hbytes > region0) region0 = hbytes;

    ushort_t* h2u   = (ushort_t*)d_ws;
    ushort_t* h1u   = h2u + (size_t)N * 64;
    uint2* stg8     = (uint2*)d_ws;                   // phase 1
    uint_t* kU      = (uint_t*)((char*)d_ws + region0);
    ushort_t* srcU  = (ushort_t*)(kU + (size_t)E);
    int* off        = (int*)(((size_t)(srcU + (size_t)E) + 3) & ~(size_t)3);
    int* bcount     = off + (N + 1);
    int* bbase      = bcount + NB2;
    int* bcur       = bbase + NB2 + 1;
    char* wp        = (char*)(bcur + NB2 * BCPAD);
    wp = (char*)(((size_t)wp + 15) & ~(size_t)15);
    uint4* wpkA     = (uint4*)wp;
    uint4* wpkB     = wpkA + 1024;

    hipMemsetAsync(bcount, 0, NB2 * sizeof(int), stream);
    bhist_kernel<<<HROWS, 256, 0, stream>>>(ei, bcount, E);
    bscan_kernel<<<1, NB2, 0, stream>>>(bcount, bbase, bcur, off,
                                        nbuck, E, N, W2a, W2b, wpkA, wpkB);

    int ablocks = (E + CHUNK - 1) / CHUNK;
    partA_kernel<<<ablocks, 512, 0, stream>>>(K, ei, bcur, stg8, E);
    partB_kernel<<<nbuck, 256, 0, stream>>>(stg8, bbase, off, srcU, kU, N);

    conv1_mlp1_kernel<<<(N + 7) / 8, 256, 0, stream>>>(x, srcU, kU, off,
                                                       W1, b1, h1u, N);
    conv2_gather_kernel<<<(N + 3) / 4, 256, 0, stream>>>(h1u, srcU, kU, off,
                                                         h2u, N);
    mlp2_kernel<<<(N + 63) / 64, 256, 0, stream>>>(h2u, wpkA, b2a, wpkB, b2b,
                                                   out, N);
}